// Round 1
// baseline (1180.436 us; speedup 1.0000x reference)
//
#include <hip/hip_runtime.h>
#include <math.h>

#define D_IN   768
#define D_OUT  768
#define NHEAD  12
#define HDIM   64
#define SEQ    1024
#define BATCH  8
#define MTOT   (BATCH*SEQ)   // 8192

// ---------------------------------------------------------------------------
// GEMM: C[M,N] = A[M,K] @ B[K,N] + bias[N]   (all fp32, row-major)
// 64x64 block tile, 256 threads, 4x4 per thread, K_T=16, A transposed in LDS.
// ---------------------------------------------------------------------------
__global__ __launch_bounds__(256) void gemm_bias_f32(
    const float* __restrict__ A, const float* __restrict__ B,
    const float* __restrict__ bias, float* __restrict__ C,
    int M, int N, int K)
{
    __shared__ __align__(16) float As[16][68];   // As[k][row]
    __shared__ __align__(16) float Bs[16][68];   // Bs[k][col]

    const int t   = threadIdx.x;
    const int ty  = t >> 4;          // 0..15
    const int tx  = t & 15;          // 0..15
    const int row0 = blockIdx.y * 64;
    const int col0 = blockIdx.x * 64;

    float acc[4][4] = {};

    for (int k0 = 0; k0 < K; k0 += 16) {
        // A tile: 64 rows x 16 k. thread t: row=t>>2, kquad=(t&3)*4
        {
            const int r  = t >> 2;
            const int kq = (t & 3) * 4;
            const float4 a4 = *(const float4*)(A + (size_t)(row0 + r) * K + k0 + kq);
            As[kq + 0][r] = a4.x;
            As[kq + 1][r] = a4.y;
            As[kq + 2][r] = a4.z;
            As[kq + 3][r] = a4.w;
        }
        // B tile: 16 k-rows x 64 cols. thread t: krow=t>>4, col=(t&15)*4
        {
            const int kr = t >> 4;
            const int c  = (t & 15) * 4;
            *(float4*)&Bs[kr][c] = *(const float4*)(B + (size_t)(k0 + kr) * N + col0 + c);
        }
        __syncthreads();

        #pragma unroll
        for (int kk = 0; kk < 16; ++kk) {
            const float4 a4 = *(const float4*)&As[kk][ty * 4];
            const float4 b4 = *(const float4*)&Bs[kk][tx * 4];
            const float av[4] = {a4.x, a4.y, a4.z, a4.w};
            const float bv[4] = {b4.x, b4.y, b4.z, b4.w};
            #pragma unroll
            for (int i = 0; i < 4; ++i)
                #pragma unroll
                for (int j = 0; j < 4; ++j)
                    acc[i][j] += av[i] * bv[j];
        }
        __syncthreads();
    }

    #pragma unroll
    for (int i = 0; i < 4; ++i) {
        const int r = row0 + ty * 4 + i;
        const int c = col0 + tx * 4;
        float4 o;
        o.x = acc[i][0] + bias[c + 0];
        o.y = acc[i][1] + bias[c + 1];
        o.z = acc[i][2] + bias[c + 2];
        o.w = acc[i][3] + bias[c + 3];
        *(float4*)(C + (size_t)r * N + c) = o;
    }
}

// ---------------------------------------------------------------------------
// Flash-style attention, fp32.
// grid = (SEQ/64, BATCH*NHEAD), 256 threads.
// Per block: 64 q-rows of one (b,h). K-tiles of 64 keys, online softmax.
// thread t: rg=t>>3 owns q-rows {rg, rg+32}; g=t&7 owns keys {g,g+8,...,g+56}
// and output dims {g*8 .. g*8+7}.
// LDS rows padded to 68 floats => conflict-free per access-pattern analysis.
// ---------------------------------------------------------------------------
__global__ __launch_bounds__(256) void attn_f32(
    const float* __restrict__ Q, const float* __restrict__ K,
    const float* __restrict__ V, float* __restrict__ O)
{
    __shared__ __align__(16) float Qs[64][68];
    __shared__ __align__(16) float Ks[64][68];
    __shared__ __align__(16) float Vs[64][68];
    __shared__ __align__(16) float Ss[64][68];

    const int t  = threadIdx.x;
    const int rg = t >> 3;   // 0..31
    const int g  = t & 7;    // 0..7

    const int bh = blockIdx.y;
    const int b  = bh / NHEAD;
    const int h  = bh % NHEAD;
    const int q0 = blockIdx.x * 64;
    const float scale = 0.125f;   // 1/sqrt(64)

    const size_t base = ((size_t)b * SEQ) * D_OUT + (size_t)h * HDIM;

    // load Q tile: 64 rows x 64 cols; thread t: row=t>>2, chunk=(t&3)*16
    {
        const int r  = t >> 2;
        const int c0 = (t & 3) * 16;
        const float* src = Q + base + (size_t)(q0 + r) * D_OUT + c0;
        #pragma unroll
        for (int u = 0; u < 4; ++u)
            *(float4*)&Qs[r][c0 + u * 4] = *(const float4*)(src + u * 4);
    }

    float m[2] = {-INFINITY, -INFINITY};
    float l[2] = {0.0f, 0.0f};
    float o[2][8] = {};

    for (int kt = 0; kt < SEQ / 64; ++kt) {
        const int k0 = kt * 64;
        // load K/V tiles
        {
            const int r  = t >> 2;
            const int c0 = (t & 3) * 16;
            const float* srck = K + base + (size_t)(k0 + r) * D_OUT + c0;
            const float* srcv = V + base + (size_t)(k0 + r) * D_OUT + c0;
            #pragma unroll
            for (int u = 0; u < 4; ++u) {
                *(float4*)&Ks[r][c0 + u * 4] = *(const float4*)(srck + u * 4);
                *(float4*)&Vs[r][c0 + u * 4] = *(const float4*)(srcv + u * 4);
            }
        }
        __syncthreads();

        // ---- scores: acc[2][8] = Q[rg/rg+32] . K[g+8ki] ----
        float acc[2][8] = {};
        #pragma unroll
        for (int d4 = 0; d4 < 16; ++d4) {
            const float4 qa = *(const float4*)&Qs[rg][d4 * 4];
            const float4 qb = *(const float4*)&Qs[rg + 32][d4 * 4];
            #pragma unroll
            for (int ki = 0; ki < 8; ++ki) {
                const float4 k4 = *(const float4*)&Ks[g + 8 * ki][d4 * 4];
                acc[0][ki] += qa.x * k4.x + qa.y * k4.y + qa.z * k4.z + qa.w * k4.w;
                acc[1][ki] += qb.x * k4.x + qb.y * k4.y + qb.z * k4.z + qb.w * k4.w;
            }
        }

        // ---- online softmax (reduce across the 8-lane g-group) ----
        #pragma unroll
        for (int r = 0; r < 2; ++r) {
            #pragma unroll
            for (int ki = 0; ki < 8; ++ki) acc[r][ki] *= scale;
            float tmax = acc[r][0];
            #pragma unroll
            for (int ki = 1; ki < 8; ++ki) tmax = fmaxf(tmax, acc[r][ki]);
            #pragma unroll
            for (int off = 1; off < 8; off <<= 1)
                tmax = fmaxf(tmax, __shfl_xor(tmax, off));

            const float mnew = fmaxf(m[r], tmax);
            const float corr = __expf(m[r] - mnew);   // m==-inf -> 0
            float psum = 0.0f;
            float p[8];
            #pragma unroll
            for (int ki = 0; ki < 8; ++ki) {
                p[ki] = __expf(acc[r][ki] - mnew);
                psum += p[ki];
            }
            #pragma unroll
            for (int off = 1; off < 8; off <<= 1)
                psum += __shfl_xor(psum, off);

            l[r] = l[r] * corr + psum;
            #pragma unroll
            for (int j = 0; j < 8; ++j) o[r][j] *= corr;
            m[r] = mnew;

            const int row = rg + 32 * r;
            #pragma unroll
            for (int ki = 0; ki < 8; ++ki)
                Ss[row][g + 8 * ki] = p[ki];
        }
        __syncthreads();

        // ---- PV: o[r][0..7] += sum_k Ss[row][k] * Vs[k][g*8 + j] ----
        #pragma unroll
        for (int k4 = 0; k4 < 16; ++k4) {
            const float4 pa = *(const float4*)&Ss[rg][k4 * 4];
            const float4 pb = *(const float4*)&Ss[rg + 32][k4 * 4];
            const float pav[4] = {pa.x, pa.y, pa.z, pa.w};
            const float pbv[4] = {pb.x, pb.y, pb.z, pb.w};
            #pragma unroll
            for (int u = 0; u < 4; ++u) {
                const int k = k4 * 4 + u;
                const float4 v0 = *(const float4*)&Vs[k][g * 8];
                const float4 v1 = *(const float4*)&Vs[k][g * 8 + 4];
                o[0][0] += pav[u] * v0.x;  o[0][1] += pav[u] * v0.y;
                o[0][2] += pav[u] * v0.z;  o[0][3] += pav[u] * v0.w;
                o[0][4] += pav[u] * v1.x;  o[0][5] += pav[u] * v1.y;
                o[0][6] += pav[u] * v1.z;  o[0][7] += pav[u] * v1.w;
                o[1][0] += pbv[u] * v0.x;  o[1][1] += pbv[u] * v0.y;
                o[1][2] += pbv[u] * v0.z;  o[1][3] += pbv[u] * v0.w;
                o[1][4] += pbv[u] * v1.x;  o[1][5] += pbv[u] * v1.y;
                o[1][6] += pbv[u] * v1.z;  o[1][7] += pbv[u] * v1.w;
            }
        }
        __syncthreads();
    }

    // normalize + store ctx (layout (b, n, h, d) flattened = (8192, 768))
    #pragma unroll
    for (int r = 0; r < 2; ++r) {
        const float inv = 1.0f / l[r];
        const int row = rg + 32 * r;
        float4 o0, o1;
        o0.x = o[r][0] * inv; o0.y = o[r][1] * inv;
        o0.z = o[r][2] * inv; o0.w = o[r][3] * inv;
        o1.x = o[r][4] * inv; o1.y = o[r][5] * inv;
        o1.z = o[r][6] * inv; o1.w = o[r][7] * inv;
        float* dst = O + base + (size_t)(q0 + row) * D_OUT + g * 8;
        *(float4*)(dst + 0) = o0;
        *(float4*)(dst + 4) = o1;
    }
}

// ---------------------------------------------------------------------------
extern "C" void kernel_launch(void* const* d_in, const int* in_sizes, int n_in,
                              void* d_out, int out_size, void* d_ws, size_t ws_size,
                              hipStream_t stream) {
    const float* x  = (const float*)d_in[0];
    const float* Wq = (const float*)d_in[1];
    const float* bq = (const float*)d_in[2];
    const float* Wk = (const float*)d_in[3];
    const float* bk = (const float*)d_in[4];
    const float* Wv = (const float*)d_in[5];
    const float* bv = (const float*)d_in[6];
    const float* Wo = (const float*)d_in[7];
    const float* bo = (const float*)d_in[8];
    float* out = (float*)d_out;

    const size_t SZ = (size_t)MTOT * D_OUT * sizeof(float);   // 25.17 MB
    char* ws = (char*)d_ws;

    float *Qb, *Kb, *Vb, *Cb;
    if (ws_size >= 4 * SZ) {
        Qb = (float*)(ws);
        Kb = (float*)(ws + SZ);
        Vb = (float*)(ws + 2 * SZ);
        Cb = (float*)(ws + 3 * SZ);
    } else {
        // Q lives in d_out (free until the final projection), rest in ws.
        Qb = out;
        Kb = (float*)(ws);
        Vb = (float*)(ws + SZ);
        Cb = (float*)(ws + 2 * SZ);
    }

    dim3 gblk(256);
    dim3 ggrid(D_OUT / 64, MTOT / 64);   // (12, 128)

    hipLaunchKernelGGL(gemm_bias_f32, ggrid, gblk, 0, stream,
                       x, Wq, bq, Qb, MTOT, D_OUT, D_IN);
    hipLaunchKernelGGL(gemm_bias_f32, ggrid, gblk, 0, stream,
                       x, Wk, bk, Kb, MTOT, D_OUT, D_IN);
    hipLaunchKernelGGL(gemm_bias_f32, ggrid, gblk, 0, stream,
                       x, Wv, bv, Vb, MTOT, D_OUT, D_IN);

    dim3 ablk(256);
    dim3 agrid(SEQ / 64, BATCH * NHEAD);  // (16, 96)
    hipLaunchKernelGGL(attn_f32, agrid, ablk, 0, stream, Qb, Kb, Vb, Cb);

    hipLaunchKernelGGL(gemm_bias_f32, ggrid, gblk, 0, stream,
                       Cb, Wo, bo, out, MTOT, D_OUT, D_IN);
}

// Round 2
// 635.605 us; speedup vs baseline: 1.8572x; 1.8572x over previous
//
#include <hip/hip_runtime.h>
#include <math.h>

#define D_MODEL 768
#define NHEAD  12
#define HDIM   64
#define SEQ    1024
#define BATCH  8
#define MTOT   (BATCH*SEQ)   // 8192

typedef _Float16 f16;
typedef __attribute__((ext_vector_type(8))) _Float16 f16x8;
typedef __attribute__((ext_vector_type(4))) float f32x4;

// ---------------------------------------------------------------------------
// GEMM: C[M,N] = A[M,K] @ B[K,N] + bias[N]   (all fp32, row-major)
// ---------------------------------------------------------------------------
__global__ __launch_bounds__(256) void gemm_bias_f32(
    const float* __restrict__ A, const float* __restrict__ B,
    const float* __restrict__ bias, float* __restrict__ C,
    int M, int N, int K)
{
    __shared__ __align__(16) float As[16][68];   // As[k][row]
    __shared__ __align__(16) float Bs[16][68];   // Bs[k][col]

    const int t   = threadIdx.x;
    const int ty  = t >> 4;
    const int tx  = t & 15;
    const int row0 = blockIdx.y * 64;
    const int col0 = blockIdx.x * 64;

    float acc[4][4] = {};

    for (int k0 = 0; k0 < K; k0 += 16) {
        {
            const int r  = t >> 2;
            const int kq = (t & 3) * 4;
            const float4 a4 = *(const float4*)(A + (size_t)(row0 + r) * K + k0 + kq);
            As[kq + 0][r] = a4.x;
            As[kq + 1][r] = a4.y;
            As[kq + 2][r] = a4.z;
            As[kq + 3][r] = a4.w;
        }
        {
            const int kr = t >> 4;
            const int c  = (t & 15) * 4;
            *(float4*)&Bs[kr][c] = *(const float4*)(B + (size_t)(k0 + kr) * N + col0 + c);
        }
        __syncthreads();

        #pragma unroll
        for (int kk = 0; kk < 16; ++kk) {
            const float4 a4 = *(const float4*)&As[kk][ty * 4];
            const float4 b4 = *(const float4*)&Bs[kk][tx * 4];
            const float av[4] = {a4.x, a4.y, a4.z, a4.w};
            const float bv[4] = {b4.x, b4.y, b4.z, b4.w};
            #pragma unroll
            for (int i = 0; i < 4; ++i)
                #pragma unroll
                for (int j = 0; j < 4; ++j)
                    acc[i][j] += av[i] * bv[j];
        }
        __syncthreads();
    }

    #pragma unroll
    for (int i = 0; i < 4; ++i) {
        const int r = row0 + ty * 4 + i;
        const int c = col0 + tx * 4;
        float4 o;
        o.x = acc[i][0] + bias[c + 0];
        o.y = acc[i][1] + bias[c + 1];
        o.z = acc[i][2] + bias[c + 2];
        o.w = acc[i][3] + bias[c + 3];
        *(float4*)(C + (size_t)r * N + c) = o;
    }
}

// ---------------------------------------------------------------------------
// Flash attention with f16 MFMA (mfma_f32_16x16x32_f16).
// grid = (SEQ/128, BATCH*NHEAD), 256 threads = 4 waves, 32 q-rows/wave.
// ---------------------------------------------------------------------------
#define LDT 72   // padded leading dim in f16 elems (row stride 144 B)

__global__ __launch_bounds__(256) void attn_f16_mfma(
    const float* __restrict__ Q, const float* __restrict__ K,
    const float* __restrict__ V, float* __restrict__ O)
{
    __shared__ f16 Ks[64][LDT];    // Ks[k][d]
    __shared__ f16 Vt[64][LDT];    // Vt[d][k]  (transposed)
    __shared__ f16 Ps[128][LDT];   // Ps[q][k], rows [32w,32w+32) private to wave w

    const int t   = threadIdx.x;
    const int w   = t >> 6;
    const int l   = t & 63;
    const int l15 = l & 15;
    const int lg  = l >> 4;

    const int bh = blockIdx.y;
    const int b  = bh / NHEAD;
    const int h  = bh % NHEAD;
    const int q0 = blockIdx.x * 128;
    const float scale = 0.125f;    // 1/sqrt(64)

    const size_t rowbase = (size_t)b * SEQ;
    const int colbase = h * HDIM;

    // ---- hoist Q fragments (A operand) ----
    f16x8 qf[2][2];
    #pragma unroll
    for (int sub = 0; sub < 2; ++sub) {
        #pragma unroll
        for (int dc = 0; dc < 2; ++dc) {
            const float* src = Q + (rowbase + q0 + w * 32 + sub * 16 + l15) * D_MODEL
                                 + colbase + dc * 32 + lg * 8;
            const float4 a = *(const float4*)(src);
            const float4 c = *(const float4*)(src + 4);
            f16x8 v;
            v[0] = (f16)a.x; v[1] = (f16)a.y; v[2] = (f16)a.z; v[3] = (f16)a.w;
            v[4] = (f16)c.x; v[5] = (f16)c.y; v[6] = (f16)c.z; v[7] = (f16)c.w;
            qf[sub][dc] = v;
        }
    }

    f32x4 ctx[2][4];
    #pragma unroll
    for (int s2 = 0; s2 < 2; ++s2)
        #pragma unroll
        for (int d2 = 0; d2 < 4; ++d2)
            ctx[s2][d2] = (f32x4){0.f, 0.f, 0.f, 0.f};
    float mrow[2][4], lrow[2][4];
    #pragma unroll
    for (int s2 = 0; s2 < 2; ++s2)
        #pragma unroll
        for (int j = 0; j < 4; ++j) { mrow[s2][j] = -INFINITY; lrow[s2][j] = 0.f; }

    for (int kt = 0; kt < SEQ / 64; ++kt) {
        const int k0 = kt * 64;
        __syncthreads();

        // ---- stage K (row-major) and V (transposed), fp32 -> f16 ----
        {
            const int r  = t & 63;
            const int cb = (t >> 6) * 16;
            const float* kp = K + (rowbase + k0 + r) * D_MODEL + colbase + cb;
            const float* vp = V + (rowbase + k0 + r) * D_MODEL + colbase + cb;
            float kv[16], vv[16];
            #pragma unroll
            for (int u = 0; u < 4; ++u) {
                const float4 k4 = *(const float4*)(kp + u * 4);
                const float4 v4 = *(const float4*)(vp + u * 4);
                kv[u*4+0] = k4.x; kv[u*4+1] = k4.y; kv[u*4+2] = k4.z; kv[u*4+3] = k4.w;
                vv[u*4+0] = v4.x; vv[u*4+1] = v4.y; vv[u*4+2] = v4.z; vv[u*4+3] = v4.w;
            }
            f16x8 kh0, kh1;
            #pragma unroll
            for (int j = 0; j < 8; ++j) { kh0[j] = (f16)kv[j]; kh1[j] = (f16)kv[8 + j]; }
            *(f16x8*)&Ks[r][cb]     = kh0;
            *(f16x8*)&Ks[r][cb + 8] = kh1;
            #pragma unroll
            for (int j = 0; j < 16; ++j)
                Vt[cb + j][r] = (f16)vv[j];
        }
        __syncthreads();

        // ---- S = Q K^T ----
        f32x4 s[2][4];
        #pragma unroll
        for (int kc = 0; kc < 4; ++kc) {
            const f16x8 kb0 = *(const f16x8*)&Ks[kc * 16 + l15][0  + lg * 8];
            const f16x8 kb1 = *(const f16x8*)&Ks[kc * 16 + l15][32 + lg * 8];
            #pragma unroll
            for (int sub = 0; sub < 2; ++sub) {
                f32x4 acc = (f32x4){0.f, 0.f, 0.f, 0.f};
                acc = __builtin_amdgcn_mfma_f32_16x16x32_f16(qf[sub][0], kb0, acc, 0, 0, 0);
                acc = __builtin_amdgcn_mfma_f32_16x16x32_f16(qf[sub][1], kb1, acc, 0, 0, 0);
                s[sub][kc] = acc;
            }
        }

        // ---- online softmax ----
        #pragma unroll
        for (int sub = 0; sub < 2; ++sub) {
            float p[4][4];
            #pragma unroll
            for (int j = 0; j < 4; ++j) {
                float tmax = fmaxf(fmaxf(s[sub][0][j], s[sub][1][j]),
                                   fmaxf(s[sub][2][j], s[sub][3][j])) * scale;
                #pragma unroll
                for (int off = 1; off < 16; off <<= 1)
                    tmax = fmaxf(tmax, __shfl_xor(tmax, off));
                const float mnew = fmaxf(mrow[sub][j], tmax);
                const float corr = __expf(mrow[sub][j] - mnew);
                mrow[sub][j] = mnew;
                float ps = 0.f;
                #pragma unroll
                for (int kc = 0; kc < 4; ++kc) {
                    p[kc][j] = __expf(s[sub][kc][j] * scale - mnew);
                    ps += p[kc][j];
                }
                #pragma unroll
                for (int off = 1; off < 16; off <<= 1)
                    ps += __shfl_xor(ps, off);
                lrow[sub][j] = lrow[sub][j] * corr + ps;
                #pragma unroll
                for (int dcol = 0; dcol < 4; ++dcol)
                    ctx[sub][dcol][j] *= corr;
            }
            #pragma unroll
            for (int kc = 0; kc < 4; ++kc)
                #pragma unroll
                for (int j = 0; j < 4; ++j)
                    Ps[w * 32 + sub * 16 + lg * 4 + j][l15 + 16 * kc] = (f16)p[kc][j];
        }

        // ---- ctx += P V ----
        #pragma unroll
        for (int kc2 = 0; kc2 < 2; ++kc2) {
            const f16x8 pa0 = *(const f16x8*)&Ps[w * 32 +  0 + l15][kc2 * 32 + lg * 8];
            const f16x8 pa1 = *(const f16x8*)&Ps[w * 32 + 16 + l15][kc2 * 32 + lg * 8];
            #pragma unroll
            for (int dcol = 0; dcol < 4; ++dcol) {
                const f16x8 vb = *(const f16x8*)&Vt[dcol * 16 + l15][kc2 * 32 + lg * 8];
                ctx[0][dcol] = __builtin_amdgcn_mfma_f32_16x16x32_f16(pa0, vb, ctx[0][dcol], 0, 0, 0);
                ctx[1][dcol] = __builtin_amdgcn_mfma_f32_16x16x32_f16(pa1, vb, ctx[1][dcol], 0, 0, 0);
            }
        }
    }

    // ---- normalize + store ----
    #pragma unroll
    for (int sub = 0; sub < 2; ++sub) {
        #pragma unroll
        for (int j = 0; j < 4; ++j) {
            const float inv = 1.0f / lrow[sub][j];
            const size_t row = rowbase + q0 + w * 32 + sub * 16 + lg * 4 + j;
            #pragma unroll
            for (int dcol = 0; dcol < 4; ++dcol)
                O[row * D_MODEL + colbase + dcol * 16 + l15] = ctx[sub][dcol][j] * inv;
        }
    }
}

// ---------------------------------------------------------------------------
extern "C" void kernel_launch(void* const* d_in, const int* in_sizes, int n_in,
                              void* d_out, int out_size, void* d_ws, size_t ws_size,
                              hipStream_t stream) {
    const float* x  = (const float*)d_in[0];
    const float* Wq = (const float*)d_in[1];
    const float* bq = (const float*)d_in[2];
    const float* Wk = (const float*)d_in[3];
    const float* bk = (const float*)d_in[4];
    const float* Wv = (const float*)d_in[5];
    const float* bv = (const float*)d_in[6];
    const float* Wo = (const float*)d_in[7];
    const float* bo = (const float*)d_in[8];
    float* out = (float*)d_out;

    const size_t SZ = (size_t)MTOT * D_MODEL * sizeof(float);   // 25.17 MB
    char* ws = (char*)d_ws;

    float *Qb, *Kb, *Vb, *Cb;
    if (ws_size >= 4 * SZ) {
        Qb = (float*)(ws);
        Kb = (float*)(ws + SZ);
        Vb = (float*)(ws + 2 * SZ);
        Cb = (float*)(ws + 3 * SZ);
    } else {
        Qb = out;
        Kb = (float*)(ws);
        Vb = (float*)(ws + SZ);
        Cb = (float*)(ws + 2 * SZ);
    }

    dim3 gblk(256);
    dim3 ggrid(D_MODEL / 64, MTOT / 64);   // (12, 128)

    hipLaunchKernelGGL(gemm_bias_f32, ggrid, gblk, 0, stream,
                       x, Wq, bq, Qb, MTOT, D_MODEL, D_MODEL);
    hipLaunchKernelGGL(gemm_bias_f32, ggrid, gblk, 0, stream,
                       x, Wk, bk, Kb, MTOT, D_MODEL, D_MODEL);
    hipLaunchKernelGGL(gemm_bias_f32, ggrid, gblk, 0, stream,
                       x, Wv, bv, Vb, MTOT, D_MODEL, D_MODEL);

    dim3 ablk(256);
    dim3 agrid(SEQ / 128, BATCH * NHEAD);  // (8, 96)
    hipLaunchKernelGGL(attn_f16_mfma, agrid, ablk, 0, stream, Qb, Kb, Vb, Cb);

    hipLaunchKernelGGL(gemm_bias_f32, ggrid, gblk, 0, stream,
                       Cb, Wo, bo, out, MTOT, D_MODEL, D_MODEL);
}

// Round 3
// 184.662 us; speedup vs baseline: 6.3924x; 3.4420x over previous
//
#include <hip/hip_runtime.h>
#include <math.h>

#define D_MODEL 768
#define NHEAD  12
#define HDIM   64
#define SEQ    1024
#define BATCH  8
#define MTOT   (BATCH*SEQ)   // 8192
#define QKV_LD 2304          // Q|K|V concatenated columns

typedef _Float16 f16;
typedef __attribute__((ext_vector_type(8))) _Float16 f16x8;
typedef __attribute__((ext_vector_type(4))) float f32x4;

__device__ inline void gload_lds16(const void* g, void* l) {
    __builtin_amdgcn_global_load_lds(
        (const __attribute__((address_space(1))) void*)g,
        (__attribute__((address_space(3))) void*)l, 16, 0, 0);
}

// ---------------------------------------------------------------------------
// x (fp32) -> f16, vectorized 8/thread
// ---------------------------------------------------------------------------
__global__ __launch_bounds__(256) void cvt_f32_f16(
    const float* __restrict__ in, f16* __restrict__ out, int n8)
{
    const int i = blockIdx.x * 256 + threadIdx.x;
    if (i < n8) {
        const float4 a = *(const float4*)(in + (size_t)i * 8);
        const float4 b = *(const float4*)(in + (size_t)i * 8 + 4);
        f16x8 v;
        v[0] = (f16)a.x; v[1] = (f16)a.y; v[2] = (f16)a.z; v[3] = (f16)a.w;
        v[4] = (f16)b.x; v[5] = (f16)b.y; v[6] = (f16)b.z; v[7] = (f16)b.w;
        *(f16x8*)(out + (size_t)i * 8) = v;
    }
}

__global__ __launch_bounds__(256) void concat_bias(
    const float* __restrict__ bq, const float* __restrict__ bk,
    const float* __restrict__ bv, float* __restrict__ bqkv)
{
    const int i = blockIdx.x * 256 + threadIdx.x;
    if (i < QKV_LD)
        bqkv[i] = (i < 768) ? bq[i] : (i < 1536) ? bk[i - 768] : bv[i - 1536];
}

// ---------------------------------------------------------------------------
// W[768][768] fp32 -> W^T[768][768] f16, LDS tile transpose
// ---------------------------------------------------------------------------
__global__ __launch_bounds__(256) void transpose_cvt_768(
    const float* __restrict__ src, f16* __restrict__ dst)
{
    __shared__ f16 tile[64][72];
    const int t  = threadIdx.x;
    const int k0 = blockIdx.y * 64;
    const int n0 = blockIdx.x * 64;
    {
        const int r  = t >> 4;
        const int c4 = (t & 15) * 4;
        #pragma unroll
        for (int u = 0; u < 4; ++u) {
            const int row = r + u * 16;
            const float4 a = *(const float4*)&src[(size_t)(k0 + row) * 768 + n0 + c4];
            tile[row][c4 + 0] = (f16)a.x;
            tile[row][c4 + 1] = (f16)a.y;
            tile[row][c4 + 2] = (f16)a.z;
            tile[row][c4 + 3] = (f16)a.w;
        }
    }
    __syncthreads();
    {
        const int rn = t >> 3;
        const int ck = (t & 7) * 8;
        #pragma unroll
        for (int u = 0; u < 2; ++u) {
            const int n = rn + u * 32;
            f16x8 v;
            #pragma unroll
            for (int q = 0; q < 8; ++q) v[q] = tile[ck + q][n];
            *(f16x8*)&dst[(size_t)(n0 + n) * 768 + k0 + ck] = v;
        }
    }
}

// ---------------------------------------------------------------------------
// C[M][N] = A[M][K]f16 @ Bt[N][K]f16^T + bias.  128x128 tile, 4 waves,
// 64x64/wave (4x4 of 16x16x32 MFMA). global_load_lds(16B) staging, both
// operands as [128 rows][32 k] with add-rotate k-slot swizzle:
//   stored slot s' of row r holds source k-chunk (s' - (r>>1)) & 3
//   reader of (r, kgroup lg) reads slot (lg + (r>>1)) & 3
// -> 2-way bank alias on ds_read_b128 (free) instead of 8-way.
// ---------------------------------------------------------------------------
template<typename OUT_T>
__global__ __launch_bounds__(256) void gemm_f16_tn(
    const f16* __restrict__ A, const f16* __restrict__ Bt,
    const float* __restrict__ bias, OUT_T* __restrict__ C,
    int M, int N, int K)
{
    __shared__ f16 As[128 * 32];
    __shared__ f16 Bs[128 * 32];

    const int t    = threadIdx.x;
    const int l    = t & 63;
    const int w    = t >> 6;
    const int l15  = l & 15;
    const int lg   = l >> 4;
    const int wrow = (w >> 1) * 64;
    const int wcol = (w & 1) * 64;
    const int row0 = blockIdx.y * 128;
    const int col0 = blockIdx.x * 128;

    // staging: 512 16B-chunks, 2 per thread; chunk c -> row c>>2, slot c&3
    int src_row[2], src_koff[2], lds_off[2];
    #pragma unroll
    for (int i = 0; i < 2; ++i) {
        const int c = t + 256 * i;
        const int r = c >> 2;
        src_row[i]  = r;
        src_koff[i] = (((c & 3) - (r >> 1)) & 3) * 8;   // source k-chunk
        lds_off[i]  = c * 16;                            // linear LDS bytes
    }

    // fragment read byte-offsets (constant across K-steps)
    int a_off[4], b_off[4];
    #pragma unroll
    for (int i = 0; i < 4; ++i) {
        const int ra = wrow + i * 16 + l15;
        a_off[i] = ra * 64 + (((lg + (ra >> 1)) & 3) * 16);
        const int rb = wcol + i * 16 + l15;
        b_off[i] = rb * 64 + (((lg + (rb >> 1)) & 3) * 16);
    }

    f32x4 acc[4][4];
    #pragma unroll
    for (int i = 0; i < 4; ++i)
        #pragma unroll
        for (int j = 0; j < 4; ++j)
            acc[i][j] = (f32x4){0.f, 0.f, 0.f, 0.f};

    const f16* Abase = A  + (size_t)row0 * K;
    const f16* Bbase = Bt + (size_t)col0 * K;

    for (int k0 = 0; k0 < K; k0 += 32) {
        #pragma unroll
        for (int i = 0; i < 2; ++i) {
            gload_lds16(Abase + (size_t)src_row[i] * K + k0 + src_koff[i],
                        (char*)As + lds_off[i]);
            gload_lds16(Bbase + (size_t)src_row[i] * K + k0 + src_koff[i],
                        (char*)Bs + lds_off[i]);
        }
        __syncthreads();   // drains vmcnt -> LDS tiles ready

        f16x8 af[4], bf[4];
        #pragma unroll
        for (int i = 0; i < 4; ++i) {
            af[i] = *(const f16x8*)((const char*)As + a_off[i]);
            bf[i] = *(const f16x8*)((const char*)Bs + b_off[i]);
        }
        #pragma unroll
        for (int i = 0; i < 4; ++i)
            #pragma unroll
            for (int j = 0; j < 4; ++j)
                acc[i][j] = __builtin_amdgcn_mfma_f32_16x16x32_f16(
                    af[i], bf[j], acc[i][j], 0, 0, 0);
        __syncthreads();   // all reads done before next-step staging
    }

    #pragma unroll
    for (int j = 0; j < 4; ++j) {
        const int col = col0 + wcol + j * 16 + l15;
        const float bj = bias[col];
        #pragma unroll
        for (int i = 0; i < 4; ++i) {
            const int row = row0 + wrow + i * 16 + lg * 4;
            #pragma unroll
            for (int q = 0; q < 4; ++q)
                C[(size_t)(row + q) * N + col] = (OUT_T)(acc[i][j][q] + bj);
        }
    }
}

// ---------------------------------------------------------------------------
// Flash attention, f16 in (QKV concat, stride 2304), f16 ctx out.
// grid = (SEQ/128, BATCH*NHEAD), 256 threads = 4 waves, 32 q-rows/wave.
// ---------------------------------------------------------------------------
#define LDT 72

__global__ __launch_bounds__(256) void attn_f16(
    const f16* __restrict__ QKV, f16* __restrict__ O)
{
    __shared__ f16 Ks[64][LDT];
    __shared__ f16 Vt[64][LDT];
    __shared__ f16 Ps[128][LDT];

    const int t   = threadIdx.x;
    const int w   = t >> 6;
    const int l   = t & 63;
    const int l15 = l & 15;
    const int lg  = l >> 4;

    const int bh = blockIdx.y;
    const int b  = bh / NHEAD;
    const int h  = bh % NHEAD;
    const int q0 = blockIdx.x * 128;
    const float scale = 0.125f;

    const size_t rowbase = (size_t)b * SEQ;
    const int qcol = h * HDIM;
    const int kcol = 768 + h * HDIM;
    const int vcol = 1536 + h * HDIM;

    // hoist Q fragments
    f16x8 qf[2][2];
    #pragma unroll
    for (int sub = 0; sub < 2; ++sub)
        #pragma unroll
        for (int dc = 0; dc < 2; ++dc)
            qf[sub][dc] = *(const f16x8*)(QKV
                + (rowbase + q0 + w * 32 + sub * 16 + l15) * QKV_LD
                + qcol + dc * 32 + lg * 8);

    f32x4 ctx[2][4];
    #pragma unroll
    for (int s2 = 0; s2 < 2; ++s2)
        #pragma unroll
        for (int d2 = 0; d2 < 4; ++d2)
            ctx[s2][d2] = (f32x4){0.f, 0.f, 0.f, 0.f};
    float mrow[2][4], lrow[2][4];
    #pragma unroll
    for (int s2 = 0; s2 < 2; ++s2)
        #pragma unroll
        for (int j = 0; j < 4; ++j) { mrow[s2][j] = -INFINITY; lrow[s2][j] = 0.f; }

    for (int kt = 0; kt < SEQ / 64; ++kt) {
        const int k0 = kt * 64;
        __syncthreads();

        {   // stage K row-major, V transposed
            const int r  = t & 63;
            const int cb = (t >> 6) * 16;
            const f16* kp = QKV + (rowbase + k0 + r) * QKV_LD + kcol + cb;
            const f16* vp = QKV + (rowbase + k0 + r) * QKV_LD + vcol + cb;
            const f16x8 kh0 = *(const f16x8*)kp;
            const f16x8 kh1 = *(const f16x8*)(kp + 8);
            *(f16x8*)&Ks[r][cb]     = kh0;
            *(f16x8*)&Ks[r][cb + 8] = kh1;
            const f16x8 v0 = *(const f16x8*)vp;
            const f16x8 v1 = *(const f16x8*)(vp + 8);
            #pragma unroll
            for (int j = 0; j < 8; ++j) {
                Vt[cb + j][r]     = v0[j];
                Vt[cb + 8 + j][r] = v1[j];
            }
        }
        __syncthreads();

        // S = Q K^T
        f32x4 s[2][4];
        #pragma unroll
        for (int kc = 0; kc < 4; ++kc) {
            const f16x8 kb0 = *(const f16x8*)&Ks[kc * 16 + l15][0  + lg * 8];
            const f16x8 kb1 = *(const f16x8*)&Ks[kc * 16 + l15][32 + lg * 8];
            #pragma unroll
            for (int sub = 0; sub < 2; ++sub) {
                f32x4 a = (f32x4){0.f, 0.f, 0.f, 0.f};
                a = __builtin_amdgcn_mfma_f32_16x16x32_f16(qf[sub][0], kb0, a, 0, 0, 0);
                a = __builtin_amdgcn_mfma_f32_16x16x32_f16(qf[sub][1], kb1, a, 0, 0, 0);
                s[sub][kc] = a;
            }
        }

        // online softmax
        #pragma unroll
        for (int sub = 0; sub < 2; ++sub) {
            float p[4][4];
            #pragma unroll
            for (int j = 0; j < 4; ++j) {
                float tmax = fmaxf(fmaxf(s[sub][0][j], s[sub][1][j]),
                                   fmaxf(s[sub][2][j], s[sub][3][j])) * scale;
                #pragma unroll
                for (int off = 1; off < 16; off <<= 1)
                    tmax = fmaxf(tmax, __shfl_xor(tmax, off));
                const float mnew = fmaxf(mrow[sub][j], tmax);
                const float corr = __expf(mrow[sub][j] - mnew);
                mrow[sub][j] = mnew;
                float ps = 0.f;
                #pragma unroll
                for (int kc = 0; kc < 4; ++kc) {
                    p[kc][j] = __expf(s[sub][kc][j] * scale - mnew);
                    ps += p[kc][j];
                }
                #pragma unroll
                for (int off = 1; off < 16; off <<= 1)
                    ps += __shfl_xor(ps, off);
                lrow[sub][j] = lrow[sub][j] * corr + ps;
                #pragma unroll
                for (int dcol = 0; dcol < 4; ++dcol)
                    ctx[sub][dcol][j] *= corr;
            }
            #pragma unroll
            for (int kc = 0; kc < 4; ++kc)
                #pragma unroll
                for (int j = 0; j < 4; ++j)
                    Ps[w * 32 + sub * 16 + lg * 4 + j][l15 + 16 * kc] = (f16)p[kc][j];
        }

        // ctx += P V
        #pragma unroll
        for (int kc2 = 0; kc2 < 2; ++kc2) {
            const f16x8 pa0 = *(const f16x8*)&Ps[w * 32 +  0 + l15][kc2 * 32 + lg * 8];
            const f16x8 pa1 = *(const f16x8*)&Ps[w * 32 + 16 + l15][kc2 * 32 + lg * 8];
            #pragma unroll
            for (int dcol = 0; dcol < 4; ++dcol) {
                const f16x8 vb = *(const f16x8*)&Vt[dcol * 16 + l15][kc2 * 32 + lg * 8];
                ctx[0][dcol] = __builtin_amdgcn_mfma_f32_16x16x32_f16(pa0, vb, ctx[0][dcol], 0, 0, 0);
                ctx[1][dcol] = __builtin_amdgcn_mfma_f32_16x16x32_f16(pa1, vb, ctx[1][dcol], 0, 0, 0);
            }
        }
    }

    // normalize + store f16 ctx (layout (b*n, 768))
    #pragma unroll
    for (int sub = 0; sub < 2; ++sub)
        #pragma unroll
        for (int j = 0; j < 4; ++j) {
            const float inv = 1.0f / lrow[sub][j];
            const size_t row = rowbase + q0 + w * 32 + sub * 16 + lg * 4 + j;
            #pragma unroll
            for (int dcol = 0; dcol < 4; ++dcol)
                O[row * D_MODEL + qcol + dcol * 16 + l15] = (f16)(ctx[sub][dcol][j] * inv);
        }
}

// ---------------------------------------------------------------------------
extern "C" void kernel_launch(void* const* d_in, const int* in_sizes, int n_in,
                              void* d_out, int out_size, void* d_ws, size_t ws_size,
                              hipStream_t stream) {
    const float* x  = (const float*)d_in[0];
    const float* Wq = (const float*)d_in[1];
    const float* bq = (const float*)d_in[2];
    const float* Wk = (const float*)d_in[3];
    const float* bk = (const float*)d_in[4];
    const float* Wv = (const float*)d_in[5];
    const float* bv = (const float*)d_in[6];
    const float* Wo = (const float*)d_in[7];
    const float* bo = (const float*)d_in[8];
    float* out = (float*)d_out;

    char* ws = (char*)d_ws;
    // layout (bytes):
    f16*   QKV     = (f16*)(ws);                                   // 8192*2304*2 = 37,748,736
    f16*   xh      = (f16*)(ws + 37748736);                        // 12,582,912
    f16*   ctxh    = (f16*)(ws + 37748736 + 12582912);             // 12,582,912
    f16*   Wqkv_t  = (f16*)(ws + 37748736 + 2 * 12582912);         // 3,538,944
    f16*   Wo_t    = (f16*)(ws + 37748736 + 2 * 12582912 + 3538944);       // 1,179,648
    float* bqkv    = (float*)(ws + 37748736 + 2 * 12582912 + 3538944 + 1179648); // 9,216

    // --- pre-pass: conversions / transposes ---
    hipLaunchKernelGGL(cvt_f32_f16, dim3(MTOT * D_MODEL / 8 / 256), dim3(256), 0, stream,
                       x, xh, MTOT * D_MODEL / 8);
    hipLaunchKernelGGL(concat_bias, dim3(9), dim3(256), 0, stream, bq, bk, bv, bqkv);
    hipLaunchKernelGGL(transpose_cvt_768, dim3(12, 12), dim3(256), 0, stream, Wq, Wqkv_t);
    hipLaunchKernelGGL(transpose_cvt_768, dim3(12, 12), dim3(256), 0, stream, Wk, Wqkv_t + 768 * 768);
    hipLaunchKernelGGL(transpose_cvt_768, dim3(12, 12), dim3(256), 0, stream, Wv, Wqkv_t + 2 * 768 * 768);
    hipLaunchKernelGGL(transpose_cvt_768, dim3(12, 12), dim3(256), 0, stream, Wo, Wo_t);

    // --- fused QKV projection: [8192,2304] = xh @ Wqkv + bias ---
    hipLaunchKernelGGL((gemm_f16_tn<f16>), dim3(QKV_LD / 128, MTOT / 128), dim3(256), 0, stream,
                       xh, Wqkv_t, bqkv, QKV, MTOT, QKV_LD, D_MODEL);

    // --- attention ---
    hipLaunchKernelGGL(attn_f16, dim3(SEQ / 128, BATCH * NHEAD), dim3(256), 0, stream,
                       QKV, ctxh);

    // --- output projection: out = ctxh @ Wo + bo (fp32 out) ---
    hipLaunchKernelGGL((gemm_f16_tn<float>), dim3(D_MODEL / 128, MTOT / 128), dim3(256), 0, stream,
                       ctxh, Wo_t, bo, out, MTOT, D_MODEL, D_MODEL);
}

// Round 4
// 162.281 us; speedup vs baseline: 7.2740x; 1.1379x over previous
//
#include <hip/hip_runtime.h>
#include <math.h>

#define D_MODEL 768
#define NHEAD  12
#define HDIM   64
#define SEQ    1024
#define BATCH  8
#define MTOT   (BATCH*SEQ)   // 8192
#define QKV_LD 2304          // Q|K|V concatenated columns

typedef _Float16 f16;
typedef __attribute__((ext_vector_type(4))) _Float16 f16x4;
typedef __attribute__((ext_vector_type(8))) _Float16 f16x8;
typedef __attribute__((ext_vector_type(4))) float f32x4;

__device__ inline void gload_lds16(const void* g, void* l) {
    __builtin_amdgcn_global_load_lds(
        (const __attribute__((address_space(1))) void*)g,
        (__attribute__((address_space(3))) void*)l, 16, 0, 0);
}

// ---------------------------------------------------------------------------
// x (fp32) -> f16, vectorized 8/thread
// ---------------------------------------------------------------------------
__global__ __launch_bounds__(256) void cvt_f32_f16(
    const float* __restrict__ in, f16* __restrict__ out, int n8)
{
    const int i = blockIdx.x * 256 + threadIdx.x;
    if (i < n8) {
        const float4 a = *(const float4*)(in + (size_t)i * 8);
        const float4 b = *(const float4*)(in + (size_t)i * 8 + 4);
        f16x8 v;
        v[0] = (f16)a.x; v[1] = (f16)a.y; v[2] = (f16)a.z; v[3] = (f16)a.w;
        v[4] = (f16)b.x; v[5] = (f16)b.y; v[6] = (f16)b.z; v[7] = (f16)b.w;
        *(f16x8*)(out + (size_t)i * 8) = v;
    }
}

__global__ __launch_bounds__(256) void concat_bias(
    const float* __restrict__ bq, const float* __restrict__ bk,
    const float* __restrict__ bv, float* __restrict__ bqkv)
{
    const int i = blockIdx.x * 256 + threadIdx.x;
    if (i < QKV_LD)
        bqkv[i] = (i < 768) ? bq[i] : (i < 1536) ? bk[i - 768] : bv[i - 1536];
}

// ---------------------------------------------------------------------------
// W[768][768] fp32 -> W^T[768][768] f16, LDS tile transpose
// ---------------------------------------------------------------------------
__global__ __launch_bounds__(256) void transpose_cvt_768(
    const float* __restrict__ src, f16* __restrict__ dst)
{
    __shared__ f16 tile[64][72];
    const int t  = threadIdx.x;
    const int k0 = blockIdx.y * 64;
    const int n0 = blockIdx.x * 64;
    {
        const int r  = t >> 4;
        const int c4 = (t & 15) * 4;
        #pragma unroll
        for (int u = 0; u < 4; ++u) {
            const int row = r + u * 16;
            const float4 a = *(const float4*)&src[(size_t)(k0 + row) * 768 + n0 + c4];
            tile[row][c4 + 0] = (f16)a.x;
            tile[row][c4 + 1] = (f16)a.y;
            tile[row][c4 + 2] = (f16)a.z;
            tile[row][c4 + 3] = (f16)a.w;
        }
    }
    __syncthreads();
    {
        const int rn = t >> 3;
        const int ck = (t & 7) * 8;
        #pragma unroll
        for (int u = 0; u < 2; ++u) {
            const int n = rn + u * 32;
            f16x8 v;
            #pragma unroll
            for (int q = 0; q < 8; ++q) v[q] = tile[ck + q][n];
            *(f16x8*)&dst[(size_t)(n0 + n) * 768 + k0 + ck] = v;
        }
    }
}

// ---------------------------------------------------------------------------
// C[M][N] = A[M][K]f16 @ Bt[N][K]f16^T + bias.  128x128 tile, 4 waves,
// 64x64/wave (4x4 of 16x16x32 MFMA). global_load_lds(16B) staging, add-rotate
// k-slot swizzle (2-way alias on ds_read_b128).
// ---------------------------------------------------------------------------
template<typename OUT_T>
__global__ __launch_bounds__(256) void gemm_f16_tn(
    const f16* __restrict__ A, const f16* __restrict__ Bt,
    const float* __restrict__ bias, OUT_T* __restrict__ C,
    int M, int N, int K)
{
    __shared__ f16 As[128 * 32];
    __shared__ f16 Bs[128 * 32];

    const int t    = threadIdx.x;
    const int l    = t & 63;
    const int w    = t >> 6;
    const int l15  = l & 15;
    const int lg   = l >> 4;
    const int wrow = (w >> 1) * 64;
    const int wcol = (w & 1) * 64;
    const int row0 = blockIdx.y * 128;
    const int col0 = blockIdx.x * 128;

    int src_row[2], src_koff[2], lds_off[2];
    #pragma unroll
    for (int i = 0; i < 2; ++i) {
        const int c = t + 256 * i;
        const int r = c >> 2;
        src_row[i]  = r;
        src_koff[i] = (((c & 3) - (r >> 1)) & 3) * 8;
        lds_off[i]  = c * 16;
    }

    int a_off[4], b_off[4];
    #pragma unroll
    for (int i = 0; i < 4; ++i) {
        const int ra = wrow + i * 16 + l15;
        a_off[i] = ra * 64 + (((lg + (ra >> 1)) & 3) * 16);
        const int rb = wcol + i * 16 + l15;
        b_off[i] = rb * 64 + (((lg + (rb >> 1)) & 3) * 16);
    }

    f32x4 acc[4][4];
    #pragma unroll
    for (int i = 0; i < 4; ++i)
        #pragma unroll
        for (int j = 0; j < 4; ++j)
            acc[i][j] = (f32x4){0.f, 0.f, 0.f, 0.f};

    const f16* Abase = A  + (size_t)row0 * K;
    const f16* Bbase = Bt + (size_t)col0 * K;

    for (int k0 = 0; k0 < K; k0 += 32) {
        #pragma unroll
        for (int i = 0; i < 2; ++i) {
            gload_lds16(Abase + (size_t)src_row[i] * K + k0 + src_koff[i],
                        (char*)As + lds_off[i]);
            gload_lds16(Bbase + (size_t)src_row[i] * K + k0 + src_koff[i],
                        (char*)Bs + lds_off[i]);
        }
        __syncthreads();

        f16x8 af[4], bf[4];
        #pragma unroll
        for (int i = 0; i < 4; ++i) {
            af[i] = *(const f16x8*)((const char*)As + a_off[i]);
            bf[i] = *(const f16x8*)((const char*)Bs + b_off[i]);
        }
        #pragma unroll
        for (int i = 0; i < 4; ++i)
            #pragma unroll
            for (int j = 0; j < 4; ++j)
                acc[i][j] = __builtin_amdgcn_mfma_f32_16x16x32_f16(
                    af[i], bf[j], acc[i][j], 0, 0, 0);
        __syncthreads();
    }

    #pragma unroll
    for (int j = 0; j < 4; ++j) {
        const int col = col0 + wcol + j * 16 + l15;
        const float bj = bias[col];
        #pragma unroll
        for (int i = 0; i < 4; ++i) {
            const int row = row0 + wrow + i * 16 + lg * 4;
            #pragma unroll
            for (int q = 0; q < 4; ++q)
                C[(size_t)(row + q) * N + col] = (OUT_T)(acc[i][j][q] + bj);
        }
    }
}

// ---------------------------------------------------------------------------
// Flash attention, f16, swapped QK^T (S^T layout -> lane-local k-rows),
// exp2-domain softmax, defer-max, register-prefetched K/V staging.
// grid = (SEQ/128, BATCH*NHEAD), 256 threads = 4 waves, 32 q-rows/wave.
// ---------------------------------------------------------------------------
#define LDT 72
#define LOG2E 1.4426950408889634f
#define RESCALE_THR 10.0f   // exp2 domain; P bounded by 2^10, safe in f16

__global__ __launch_bounds__(256) void attn_f16(
    const f16* __restrict__ QKV, f16* __restrict__ O)
{
    __shared__ f16 Ks[64][LDT];
    __shared__ f16 Vt[64][LDT];
    __shared__ f16 Ps[128][LDT];

    const int t   = threadIdx.x;
    const int w   = t >> 6;
    const int l   = t & 63;
    const int l15 = l & 15;
    const int lg  = l >> 4;

    const int bh = blockIdx.y;
    const int b  = bh / NHEAD;
    const int h  = bh % NHEAD;
    const int q0 = blockIdx.x * 128;
    const float sc2 = 0.125f * LOG2E;   // scale folded into exp2 domain

    const size_t rowbase = (size_t)b * SEQ;
    const int qcol = h * HDIM;
    const int kcol = 768 + h * HDIM;
    const int vcol = 1536 + h * HDIM;

    // ---- hoist Q fragments (B operand of swapped QK^T; same data layout) ----
    f16x8 qf[2][2];
    #pragma unroll
    for (int sub = 0; sub < 2; ++sub)
        #pragma unroll
        for (int dc = 0; dc < 2; ++dc)
            qf[sub][dc] = *(const f16x8*)(QKV
                + (rowbase + q0 + w * 32 + sub * 16 + l15) * QKV_LD
                + qcol + dc * 32 + lg * 8);

    f32x4 ctx[2][4];
    #pragma unroll
    for (int s2 = 0; s2 < 2; ++s2)
        #pragma unroll
        for (int d2 = 0; d2 < 4; ++d2)
            ctx[s2][d2] = (f32x4){0.f, 0.f, 0.f, 0.f};
    float mrun[2] = {-INFINITY, -INFINITY};
    float lrun[2] = {0.f, 0.f};

    // ---- staging pointers: row r = l, col block cb = w*16 ----
    const int cb = w * 16;
    const f16* kptr = QKV + (rowbase + l) * QKV_LD + kcol + cb;
    const f16* vptr = QKV + (rowbase + l) * QKV_LD + vcol + cb;
    const size_t step = (size_t)64 * QKV_LD;

    // prefetch tile 0 into registers
    f16x8 kr0 = *(const f16x8*)(kptr);
    f16x8 kr1 = *(const f16x8*)(kptr + 8);
    f16x8 vr0 = *(const f16x8*)(vptr);
    f16x8 vr1 = *(const f16x8*)(vptr + 8);

    for (int kt = 0; kt < SEQ / 64; ++kt) {
        if (kt) __syncthreads();   // previous tile's LDS reads done

        // ---- write staged regs to LDS (K row-major, V transposed) ----
        *(f16x8*)&Ks[l][cb]     = kr0;
        *(f16x8*)&Ks[l][cb + 8] = kr1;
        #pragma unroll
        for (int j = 0; j < 8; ++j) {
            Vt[cb + j][l]     = vr0[j];
            Vt[cb + 8 + j][l] = vr1[j];
        }
        __syncthreads();

        // ---- issue next tile's global loads (consumed next iteration) ----
        if (kt + 1 < SEQ / 64) {
            const f16* kp = kptr + (size_t)(kt + 1) * step;
            const f16* vp = vptr + (size_t)(kt + 1) * step;
            kr0 = *(const f16x8*)(kp);
            kr1 = *(const f16x8*)(kp + 8);
            vr0 = *(const f16x8*)(vp);
            vr1 = *(const f16x8*)(vp + 8);
        }

        // ---- S^T = K @ Q^T : lane holds k = kc*16+lg*4+reg for q = l15 ----
        f32x4 s[2][4];
        #pragma unroll
        for (int kc = 0; kc < 4; ++kc) {
            const f16x8 ka0 = *(const f16x8*)&Ks[kc * 16 + l15][0  + lg * 8];
            const f16x8 ka1 = *(const f16x8*)&Ks[kc * 16 + l15][32 + lg * 8];
            #pragma unroll
            for (int sub = 0; sub < 2; ++sub) {
                f32x4 a = (f32x4){0.f, 0.f, 0.f, 0.f};
                a = __builtin_amdgcn_mfma_f32_16x16x32_f16(ka0, qf[sub][0], a, 0, 0, 0);
                a = __builtin_amdgcn_mfma_f32_16x16x32_f16(ka1, qf[sub][1], a, 0, 0, 0);
                s[sub][kc] = a;
            }
        }

        // ---- softmax (exp2 domain, in-register row, defer-max) ----
        #pragma unroll
        for (int sub = 0; sub < 2; ++sub) {
            #pragma unroll
            for (int kc = 0; kc < 4; ++kc)
                s[sub][kc] *= sc2;

            float tmax = fmaxf(fmaxf(s[sub][0][0], s[sub][0][1]),
                               fmaxf(s[sub][0][2], s[sub][0][3]));
            #pragma unroll
            for (int kc = 1; kc < 4; ++kc) {
                const float a = fmaxf(fmaxf(s[sub][kc][0], s[sub][kc][1]),
                                      fmaxf(s[sub][kc][2], s[sub][kc][3]));
                tmax = fmaxf(tmax, a);
            }
            tmax = fmaxf(tmax, __shfl_xor(tmax, 16));
            tmax = fmaxf(tmax, __shfl_xor(tmax, 32));

            if (__any(tmax > mrun[sub] + RESCALE_THR)) {
                const float mnew = fmaxf(mrun[sub], tmax);
                const float corr = exp2f(mrun[sub] - mnew);
                mrun[sub] = mnew;
                lrun[sub] *= corr;
                float cr[4];
                #pragma unroll
                for (int r = 0; r < 4; ++r)
                    cr[r] = __shfl(corr, lg * 4 + r);
                #pragma unroll
                for (int dcol = 0; dcol < 4; ++dcol)
                    #pragma unroll
                    for (int r = 0; r < 4; ++r)
                        ctx[sub][dcol][r] *= cr[r];
            }

            float ps = 0.f;
            #pragma unroll
            for (int kc = 0; kc < 4; ++kc) {
                f16x4 pv;
                #pragma unroll
                for (int r = 0; r < 4; ++r) {
                    const float p = exp2f(s[sub][kc][r] - mrun[sub]);
                    ps += p;
                    pv[r] = (f16)p;
                }
                *(f16x4*)&Ps[w * 32 + sub * 16 + l15][kc * 16 + lg * 4] = pv;
            }
            ps += __shfl_xor(ps, 16);
            ps += __shfl_xor(ps, 32);
            lrun[sub] += ps;
        }

        // ---- ctx += P V  (wave-private Ps rows; same-wave LDS ordering) ----
        #pragma unroll
        for (int kc2 = 0; kc2 < 2; ++kc2) {
            const f16x8 pa0 = *(const f16x8*)&Ps[w * 32 +  0 + l15][kc2 * 32 + lg * 8];
            const f16x8 pa1 = *(const f16x8*)&Ps[w * 32 + 16 + l15][kc2 * 32 + lg * 8];
            #pragma unroll
            for (int dcol = 0; dcol < 4; ++dcol) {
                const f16x8 vb = *(const f16x8*)&Vt[dcol * 16 + l15][kc2 * 32 + lg * 8];
                ctx[0][dcol] = __builtin_amdgcn_mfma_f32_16x16x32_f16(pa0, vb, ctx[0][dcol], 0, 0, 0);
                ctx[1][dcol] = __builtin_amdgcn_mfma_f32_16x16x32_f16(pa1, vb, ctx[1][dcol], 0, 0, 0);
            }
        }
    }

    // ---- normalize + store f16 ctx (rows q = lg*4+reg per sub-tile) ----
    #pragma unroll
    for (int sub = 0; sub < 2; ++sub) {
        const float inv = 1.0f / lrun[sub];
        float iv[4];
        #pragma unroll
        for (int r = 0; r < 4; ++r)
            iv[r] = __shfl(inv, lg * 4 + r);
        #pragma unroll
        for (int r = 0; r < 4; ++r) {
            const size_t row = rowbase + q0 + w * 32 + sub * 16 + lg * 4 + r;
            #pragma unroll
            for (int dcol = 0; dcol < 4; ++dcol)
                O[row * D_MODEL + qcol + dcol * 16 + l15] = (f16)(ctx[sub][dcol][r] * iv[r]);
        }
    }
}

// ---------------------------------------------------------------------------
extern "C" void kernel_launch(void* const* d_in, const int* in_sizes, int n_in,
                              void* d_out, int out_size, void* d_ws, size_t ws_size,
                              hipStream_t stream) {
    const float* x  = (const float*)d_in[0];
    const float* Wq = (const float*)d_in[1];
    const float* bq = (const float*)d_in[2];
    const float* Wk = (const float*)d_in[3];
    const float* bk = (const float*)d_in[4];
    const float* Wv = (const float*)d_in[5];
    const float* bv = (const float*)d_in[6];
    const float* Wo = (const float*)d_in[7];
    const float* bo = (const float*)d_in[8];
    float* out = (float*)d_out;

    char* ws = (char*)d_ws;
    f16*   QKV     = (f16*)(ws);                                   // 37,748,736 B
    f16*   xh      = (f16*)(ws + 37748736);                        // 12,582,912
    f16*   ctxh    = (f16*)(ws + 37748736 + 12582912);             // 12,582,912
    f16*   Wqkv_t  = (f16*)(ws + 37748736 + 2 * 12582912);         // 3,538,944
    f16*   Wo_t    = (f16*)(ws + 37748736 + 2 * 12582912 + 3538944);       // 1,179,648
    float* bqkv    = (float*)(ws + 37748736 + 2 * 12582912 + 3538944 + 1179648);

    hipLaunchKernelGGL(cvt_f32_f16, dim3(MTOT * D_MODEL / 8 / 256), dim3(256), 0, stream,
                       x, xh, MTOT * D_MODEL / 8);
    hipLaunchKernelGGL(concat_bias, dim3(9), dim3(256), 0, stream, bq, bk, bv, bqkv);
    hipLaunchKernelGGL(transpose_cvt_768, dim3(12, 12), dim3(256), 0, stream, Wq, Wqkv_t);
    hipLaunchKernelGGL(transpose_cvt_768, dim3(12, 12), dim3(256), 0, stream, Wk, Wqkv_t + 768 * 768);
    hipLaunchKernelGGL(transpose_cvt_768, dim3(12, 12), dim3(256), 0, stream, Wv, Wqkv_t + 2 * 768 * 768);
    hipLaunchKernelGGL(transpose_cvt_768, dim3(12, 12), dim3(256), 0, stream, Wo, Wo_t);

    hipLaunchKernelGGL((gemm_f16_tn<f16>), dim3(QKV_LD / 128, MTOT / 128), dim3(256), 0, stream,
                       xh, Wqkv_t, bqkv, QKV, MTOT, QKV_LD, D_MODEL);

    hipLaunchKernelGGL(attn_f16, dim3(SEQ / 128, BATCH * NHEAD), dim3(256), 0, stream,
                       QKV, ctxh);

    hipLaunchKernelGGL((gemm_f16_tn<float>), dim3(D_MODEL / 128, MTOT / 128), dim3(256), 0, stream,
                       ctxh, Wo_t, bo, out, MTOT, D_MODEL, D_MODEL);
}

// Round 5
// 154.414 us; speedup vs baseline: 7.6446x; 1.0509x over previous
//
#include <hip/hip_runtime.h>
#include <math.h>

#define D_MODEL 768
#define NHEAD  12
#define HDIM   64
#define SEQ    1024
#define BATCH  8
#define MTOT   (BATCH*SEQ)   // 8192
#define QKV_LD 2304          // Q|K|V concatenated columns

typedef _Float16 f16;
typedef __attribute__((ext_vector_type(4))) _Float16 f16x4;
typedef __attribute__((ext_vector_type(8))) _Float16 f16x8;
typedef __attribute__((ext_vector_type(4))) float f32x4;

__device__ inline void gload_lds16(const void* g, void* l) {
    __builtin_amdgcn_global_load_lds(
        (const __attribute__((address_space(1))) void*)g,
        (__attribute__((address_space(3))) void*)l, 16, 0, 0);
}

// ---------------------------------------------------------------------------
// x (fp32) -> f16, vectorized 8/thread
// ---------------------------------------------------------------------------
__global__ __launch_bounds__(256) void cvt_f32_f16(
    const float* __restrict__ in, f16* __restrict__ out, int n8)
{
    const int i = blockIdx.x * 256 + threadIdx.x;
    if (i < n8) {
        const float4 a = *(const float4*)(in + (size_t)i * 8);
        const float4 b = *(const float4*)(in + (size_t)i * 8 + 4);
        f16x8 v;
        v[0] = (f16)a.x; v[1] = (f16)a.y; v[2] = (f16)a.z; v[3] = (f16)a.w;
        v[4] = (f16)b.x; v[5] = (f16)b.y; v[6] = (f16)b.z; v[7] = (f16)b.w;
        *(f16x8*)(out + (size_t)i * 8) = v;
    }
}

__global__ __launch_bounds__(256) void concat_bias(
    const float* __restrict__ bq, const float* __restrict__ bk,
    const float* __restrict__ bv, float* __restrict__ bqkv)
{
    const int i = blockIdx.x * 256 + threadIdx.x;
    if (i < QKV_LD)
        bqkv[i] = (i < 768) ? bq[i] : (i < 1536) ? bk[i - 768] : bv[i - 1536];
}

// ---------------------------------------------------------------------------
// W[768][768] fp32 -> W^T[768][768] f16, LDS tile transpose
// ---------------------------------------------------------------------------
__global__ __launch_bounds__(256) void transpose_cvt_768(
    const float* __restrict__ src, f16* __restrict__ dst)
{
    __shared__ f16 tile[64][72];
    const int t  = threadIdx.x;
    const int k0 = blockIdx.y * 64;
    const int n0 = blockIdx.x * 64;
    {
        const int r  = t >> 4;
        const int c4 = (t & 15) * 4;
        #pragma unroll
        for (int u = 0; u < 4; ++u) {
            const int row = r + u * 16;
            const float4 a = *(const float4*)&src[(size_t)(k0 + row) * 768 + n0 + c4];
            tile[row][c4 + 0] = (f16)a.x;
            tile[row][c4 + 1] = (f16)a.y;
            tile[row][c4 + 2] = (f16)a.z;
            tile[row][c4 + 3] = (f16)a.w;
        }
    }
    __syncthreads();
    {
        const int rn = t >> 3;
        const int ck = (t & 7) * 8;
        #pragma unroll
        for (int u = 0; u < 2; ++u) {
            const int n = rn + u * 32;
            f16x8 v;
            #pragma unroll
            for (int q = 0; q < 8; ++q) v[q] = tile[ck + q][n];
            *(f16x8*)&dst[(size_t)(n0 + n) * 768 + k0 + ck] = v;
        }
    }
}

// ---------------------------------------------------------------------------
// C[M][N] = A[M][K]f16 @ Bt[N][K]f16^T + bias.  128x128 tile, 4 waves,
// 64x64/wave. global_load_lds(16B) staging, add-rotate k-slot swizzle.
// 1D grid with XCD-contiguous chunk mapping (grid % 8 == 0).
// ---------------------------------------------------------------------------
template<typename OUT_T>
__global__ __launch_bounds__(256) void gemm_f16_tn(
    const f16* __restrict__ A, const f16* __restrict__ Bt,
    const float* __restrict__ bias, OUT_T* __restrict__ C,
    int M, int N, int K, int nb)
{
    __shared__ f16 As[128 * 32];
    __shared__ f16 Bs[128 * 32];

    const int t    = threadIdx.x;
    const int l    = t & 63;
    const int w    = t >> 6;
    const int l15  = l & 15;
    const int lg   = l >> 4;
    const int wrow = (w >> 1) * 64;
    const int wcol = (w & 1) * 64;

    const int orig = blockIdx.x;
    const int cpx  = gridDim.x >> 3;               // blocks per XCD chunk
    const int nid  = (orig & 7) * cpx + (orig >> 3);
    const int row0 = (nid / nb) * 128;
    const int col0 = (nid % nb) * 128;

    int src_row[2], src_koff[2], lds_off[2];
    #pragma unroll
    for (int i = 0; i < 2; ++i) {
        const int c = t + 256 * i;
        const int r = c >> 2;
        src_row[i]  = r;
        src_koff[i] = (((c & 3) - (r >> 1)) & 3) * 8;
        lds_off[i]  = c * 16;
    }

    int a_off[4], b_off[4];
    #pragma unroll
    for (int i = 0; i < 4; ++i) {
        const int ra = wrow + i * 16 + l15;
        a_off[i] = ra * 64 + (((lg + (ra >> 1)) & 3) * 16);
        const int rb = wcol + i * 16 + l15;
        b_off[i] = rb * 64 + (((lg + (rb >> 1)) & 3) * 16);
    }

    f32x4 acc[4][4];
    #pragma unroll
    for (int i = 0; i < 4; ++i)
        #pragma unroll
        for (int j = 0; j < 4; ++j)
            acc[i][j] = (f32x4){0.f, 0.f, 0.f, 0.f};

    const f16* Abase = A  + (size_t)row0 * K;
    const f16* Bbase = Bt + (size_t)col0 * K;

    for (int k0 = 0; k0 < K; k0 += 32) {
        #pragma unroll
        for (int i = 0; i < 2; ++i) {
            gload_lds16(Abase + (size_t)src_row[i] * K + k0 + src_koff[i],
                        (char*)As + lds_off[i]);
            gload_lds16(Bbase + (size_t)src_row[i] * K + k0 + src_koff[i],
                        (char*)Bs + lds_off[i]);
        }
        __syncthreads();

        f16x8 af[4], bf[4];
        #pragma unroll
        for (int i = 0; i < 4; ++i) {
            af[i] = *(const f16x8*)((const char*)As + a_off[i]);
            bf[i] = *(const f16x8*)((const char*)Bs + b_off[i]);
        }
        #pragma unroll
        for (int i = 0; i < 4; ++i)
            #pragma unroll
            for (int j = 0; j < 4; ++j)
                acc[i][j] = __builtin_amdgcn_mfma_f32_16x16x32_f16(
                    af[i], bf[j], acc[i][j], 0, 0, 0);
        __syncthreads();
    }

    #pragma unroll
    for (int j = 0; j < 4; ++j) {
        const int col = col0 + wcol + j * 16 + l15;
        const float bj = bias[col];
        #pragma unroll
        for (int i = 0; i < 4; ++i) {
            const int row = row0 + wrow + i * 16 + lg * 4;
            #pragma unroll
            for (int q = 0; q < 4; ++q)
                C[(size_t)(row + q) * N + col] = (OUT_T)(acc[i][j][q] + bj);
        }
    }
}

// ---------------------------------------------------------------------------
// Flash attention, f16, swapped QK^T, exp2 softmax w/ defer-max,
// XOR-swizzled unpadded LDS (T2), double-buffered K/V (1 barrier/kt),
// scale folded into Q, setprio around MFMA clusters.
// grid = 768 1D (XCD-contiguous: 8 q-blocks of a (b,h) on one XCD).
// ---------------------------------------------------------------------------
#define RESCALE_THR 10.0f   // exp2 domain; P bounded by 2^10, safe in f16

__global__ __launch_bounds__(256) void attn_f16(
    const f16* __restrict__ QKV, f16* __restrict__ O)
{
    __shared__ f16 KsB[2][64 * 64];
    __shared__ f16 VtB[2][64 * 64];
    __shared__ f16 PsB[128 * 64];

    const int t   = threadIdx.x;
    const int w   = t >> 6;
    const int l   = t & 63;
    const int l15 = l & 15;
    const int lg  = l >> 4;
    const int sl  = (l15 & 7) << 4;   // read-side XOR slot

    const int orig = blockIdx.x;                 // 0..767
    const int s    = (orig & 7) * 96 + (orig >> 3);
    const int bh   = s >> 3;
    const int qb   = s & 7;
    const int b  = bh / NHEAD;
    const int h  = bh % NHEAD;
    const int q0 = qb * 128;

    const size_t rowbase = (size_t)b * SEQ;
    const int qcol = h * HDIM;
    const int kcol = 768 + h * HDIM;
    const int vcol = 1536 + h * HDIM;

    // ---- hoist Q fragments, fold scale*log2e into them ----
    const f16 hsc = (f16)(0.125f * 1.4426950408889634f);
    f16x8 qf[2][2];
    #pragma unroll
    for (int sub = 0; sub < 2; ++sub)
        #pragma unroll
        for (int dc = 0; dc < 2; ++dc) {
            f16x8 v = *(const f16x8*)(QKV
                + (rowbase + q0 + w * 32 + sub * 16 + l15) * QKV_LD
                + qcol + dc * 32 + lg * 8);
            #pragma unroll
            for (int j = 0; j < 8; ++j) v[j] *= hsc;
            qf[sub][dc] = v;
        }

    f32x4 ctx[2][4];
    #pragma unroll
    for (int s2 = 0; s2 < 2; ++s2)
        #pragma unroll
        for (int d2 = 0; d2 < 4; ++d2)
            ctx[s2][d2] = (f32x4){0.f, 0.f, 0.f, 0.f};
    float mrun[2] = {-INFINITY, -INFINITY};
    float lrun[2] = {0.f, 0.f};

    // ---- staging: row k = l, 16-col chunk cb = w*16 ----
    const int cb = w * 16;
    const f16* kptr = QKV + (rowbase + l) * QKV_LD + kcol + cb;
    const f16* vptr = QKV + (rowbase + l) * QKV_LD + vcol + cb;
    const size_t step = (size_t)64 * QKV_LD;

    f16x8 kr0 = *(const f16x8*)(kptr);
    f16x8 kr1 = *(const f16x8*)(kptr + 8);
    f16x8 vr0 = *(const f16x8*)(vptr);
    f16x8 vr1 = *(const f16x8*)(vptr + 8);

    // stage tile 0 -> buf 0
    {
        char* Kd = (char*)KsB[0];
        char* Vd = (char*)VtB[0];
        *(f16x8*)(Kd + l * 128 + ((cb * 2)      ^ ((l & 7) << 4))) = kr0;
        *(f16x8*)(Kd + l * 128 + ((cb * 2 + 16) ^ ((l & 7) << 4))) = kr1;
        #pragma unroll
        for (int j = 0; j < 8; ++j) {
            *(f16*)(Vd + (cb + j)     * 128 + ((l * 2) ^ (j << 4))) = vr0[j];
            *(f16*)(Vd + (cb + 8 + j) * 128 + ((l * 2) ^ (j << 4))) = vr1[j];
        }
    }
    // prefetch tile 1
    kr0 = *(const f16x8*)(kptr + step);
    kr1 = *(const f16x8*)(kptr + step + 8);
    vr0 = *(const f16x8*)(vptr + step);
    vr1 = *(const f16x8*)(vptr + step + 8);
    __syncthreads();

    for (int kt = 0; kt < SEQ / 64; ++kt) {
        const int p = kt & 1;
        const char* Kp = (const char*)KsB[p];
        const char* Vp = (const char*)VtB[p];
        char* Pp = (char*)PsB;

        // ---- S^T = K @ Q^T : lane holds k = kc*16+lg*4+r for q = l15 ----
        f32x4 sc[2][4];
        __builtin_amdgcn_s_setprio(1);
        #pragma unroll
        for (int kc = 0; kc < 4; ++kc) {
            const int rk = kc * 16 + l15;
            const f16x8 ka0 = *(const f16x8*)(Kp + rk * 128 + ((lg * 16)      ^ sl));
            const f16x8 ka1 = *(const f16x8*)(Kp + rk * 128 + ((64 + lg * 16) ^ sl));
            #pragma unroll
            for (int sub = 0; sub < 2; ++sub) {
                f32x4 a = (f32x4){0.f, 0.f, 0.f, 0.f};
                a = __builtin_amdgcn_mfma_f32_16x16x32_f16(ka0, qf[sub][0], a, 0, 0, 0);
                a = __builtin_amdgcn_mfma_f32_16x16x32_f16(ka1, qf[sub][1], a, 0, 0, 0);
                sc[sub][kc] = a;
            }
        }
        __builtin_amdgcn_s_setprio(0);

        // ---- softmax (exp2 domain, scale pre-folded, defer-max) ----
        #pragma unroll
        for (int sub = 0; sub < 2; ++sub) {
            float tmax = fmaxf(fmaxf(sc[sub][0][0], sc[sub][0][1]),
                               fmaxf(sc[sub][0][2], sc[sub][0][3]));
            #pragma unroll
            for (int kc = 1; kc < 4; ++kc)
                tmax = fmaxf(tmax, fmaxf(fmaxf(sc[sub][kc][0], sc[sub][kc][1]),
                                         fmaxf(sc[sub][kc][2], sc[sub][kc][3])));
            tmax = fmaxf(tmax, __shfl_xor(tmax, 16));
            tmax = fmaxf(tmax, __shfl_xor(tmax, 32));

            if (__any(tmax > mrun[sub] + RESCALE_THR)) {
                const float mnew = fmaxf(mrun[sub], tmax);
                const float corr = exp2f(mrun[sub] - mnew);
                mrun[sub] = mnew;
                lrun[sub] *= corr;
                float cr[4];
                #pragma unroll
                for (int r = 0; r < 4; ++r)
                    cr[r] = __shfl(corr, lg * 4 + r);
                #pragma unroll
                for (int dcol = 0; dcol < 4; ++dcol)
                    #pragma unroll
                    for (int r = 0; r < 4; ++r)
                        ctx[sub][dcol][r] *= cr[r];
            }

            float ps = 0.f;
            const int rowq = w * 32 + sub * 16 + l15;
            #pragma unroll
            for (int kc = 0; kc < 4; ++kc) {
                f16x4 pv;
                #pragma unroll
                for (int r = 0; r < 4; ++r) {
                    const float pe = exp2f(sc[sub][kc][r] - mrun[sub]);
                    ps += pe;
                    pv[r] = (f16)pe;
                }
                *(f16x4*)(Pp + rowq * 128 + ((kc * 32 + lg * 8) ^ sl)) = pv;
            }
            ps += __shfl_xor(ps, 16);
            ps += __shfl_xor(ps, 32);
            lrun[sub] += ps;
        }

        // ---- ctx += P V ----
        __builtin_amdgcn_s_setprio(1);
        #pragma unroll
        for (int kc2 = 0; kc2 < 2; ++kc2) {
            const int cbyte = (kc2 * 64 + lg * 16) ^ sl;
            const f16x8 pa0 = *(const f16x8*)(Pp + (w * 32 + l15)      * 128 + cbyte);
            const f16x8 pa1 = *(const f16x8*)(Pp + (w * 32 + 16 + l15) * 128 + cbyte);
            #pragma unroll
            for (int dcol = 0; dcol < 4; ++dcol) {
                const f16x8 vb = *(const f16x8*)(Vp + (dcol * 16 + l15) * 128 + cbyte);
                ctx[0][dcol] = __builtin_amdgcn_mfma_f32_16x16x32_f16(pa0, vb, ctx[0][dcol], 0, 0, 0);
                ctx[1][dcol] = __builtin_amdgcn_mfma_f32_16x16x32_f16(pa1, vb, ctx[1][dcol], 0, 0, 0);
            }
        }
        __builtin_amdgcn_s_setprio(0);

        // ---- stage tile kt+1 into buf p^1; issue loads for kt+2 ----
        if (kt < SEQ / 64 - 1) {
            char* Kd = (char*)KsB[p ^ 1];
            char* Vd = (char*)VtB[p ^ 1];
            *(f16x8*)(Kd + l * 128 + ((cb * 2)      ^ ((l & 7) << 4))) = kr0;
            *(f16x8*)(Kd + l * 128 + ((cb * 2 + 16) ^ ((l & 7) << 4))) = kr1;
            #pragma unroll
            for (int j = 0; j < 8; ++j) {
                *(f16*)(Vd + (cb + j)     * 128 + ((l * 2) ^ (j << 4))) = vr0[j];
                *(f16*)(Vd + (cb + 8 + j) * 128 + ((l * 2) ^ (j << 4))) = vr1[j];
            }
            if (kt < SEQ / 64 - 2) {
                const f16* kp = kptr + (size_t)(kt + 2) * step;
                const f16* vp = vptr + (size_t)(kt + 2) * step;
                kr0 = *(const f16x8*)(kp);
                kr1 = *(const f16x8*)(kp + 8);
                vr0 = *(const f16x8*)(vp);
                vr1 = *(const f16x8*)(vp + 8);
            }
        }
        __syncthreads();
    }

    // ---- normalize + store f16 ctx (rows q = lg*4+r per sub-tile) ----
    #pragma unroll
    for (int sub = 0; sub < 2; ++sub) {
        const float inv = 1.0f / lrun[sub];
        float iv[4];
        #pragma unroll
        for (int r = 0; r < 4; ++r)
            iv[r] = __shfl(inv, lg * 4 + r);
        #pragma unroll
        for (int r = 0; r < 4; ++r) {
            const size_t row = rowbase + q0 + w * 32 + sub * 16 + lg * 4 + r;
            #pragma unroll
            for (int dcol = 0; dcol < 4; ++dcol)
                O[row * D_MODEL + qcol + dcol * 16 + l15] = (f16)(ctx[sub][dcol][r] * iv[r]);
        }
    }
}

// ---------------------------------------------------------------------------
extern "C" void kernel_launch(void* const* d_in, const int* in_sizes, int n_in,
                              void* d_out, int out_size, void* d_ws, size_t ws_size,
                              hipStream_t stream) {
    const float* x  = (const float*)d_in[0];
    const float* Wq = (const float*)d_in[1];
    const float* bq = (const float*)d_in[2];
    const float* Wk = (const float*)d_in[3];
    const float* bk = (const float*)d_in[4];
    const float* Wv = (const float*)d_in[5];
    const float* bv = (const float*)d_in[6];
    const float* Wo = (const float*)d_in[7];
    const float* bo = (const float*)d_in[8];
    float* out = (float*)d_out;

    char* ws = (char*)d_ws;
    f16*   QKV     = (f16*)(ws);                                   // 37,748,736 B
    f16*   xh      = (f16*)(ws + 37748736);                        // 12,582,912
    f16*   ctxh    = (f16*)(ws + 37748736 + 12582912);             // 12,582,912
    f16*   Wqkv_t  = (f16*)(ws + 37748736 + 2 * 12582912);         // 3,538,944
    f16*   Wo_t    = (f16*)(ws + 37748736 + 2 * 12582912 + 3538944);       // 1,179,648
    float* bqkv    = (float*)(ws + 37748736 + 2 * 12582912 + 3538944 + 1179648);

    hipLaunchKernelGGL(cvt_f32_f16, dim3(MTOT * D_MODEL / 8 / 256), dim3(256), 0, stream,
                       x, xh, MTOT * D_MODEL / 8);
    hipLaunchKernelGGL(concat_bias, dim3(9), dim3(256), 0, stream, bq, bk, bv, bqkv);
    hipLaunchKernelGGL(transpose_cvt_768, dim3(12, 12), dim3(256), 0, stream, Wq, Wqkv_t);
    hipLaunchKernelGGL(transpose_cvt_768, dim3(12, 12), dim3(256), 0, stream, Wk, Wqkv_t + 768 * 768);
    hipLaunchKernelGGL(transpose_cvt_768, dim3(12, 12), dim3(256), 0, stream, Wv, Wqkv_t + 2 * 768 * 768);
    hipLaunchKernelGGL(transpose_cvt_768, dim3(12, 12), dim3(256), 0, stream, Wo, Wo_t);

    // fused QKV projection: grid 18*64 = 1152 (XCD-chunked inside kernel)
    hipLaunchKernelGGL((gemm_f16_tn<f16>), dim3((QKV_LD / 128) * (MTOT / 128)), dim3(256), 0, stream,
                       xh, Wqkv_t, bqkv, QKV, MTOT, QKV_LD, D_MODEL, QKV_LD / 128);

    hipLaunchKernelGGL(attn_f16, dim3((SEQ / 128) * BATCH * NHEAD), dim3(256), 0, stream,
                       QKV, ctxh);

    // output projection: grid 6*64 = 384
    hipLaunchKernelGGL((gemm_f16_tn<float>), dim3((D_MODEL / 128) * (MTOT / 128)), dim3(256), 0, stream,
                       ctxh, Wo_t, bo, out, MTOT, D_MODEL, D_MODEL, D_MODEL / 128);
}

// Round 7
// 145.970 us; speedup vs baseline: 8.0869x; 1.0579x over previous
//
#include <hip/hip_runtime.h>
#include <math.h>

#define D_MODEL 768
#define NHEAD  12
#define HDIM   64
#define SEQ    1024
#define BATCH  8
#define MTOT   (BATCH*SEQ)   // 8192
#define QKV_LD 2304          // Q|K|V concatenated columns

typedef _Float16 f16;
typedef __attribute__((ext_vector_type(4))) _Float16 f16x4;
typedef __attribute__((ext_vector_type(8))) _Float16 f16x8;
typedef __attribute__((ext_vector_type(4))) float f32x4;

__device__ inline void gload_lds16(const void* g, void* l) {
    __builtin_amdgcn_global_load_lds(
        (const __attribute__((address_space(1))) void*)g,
        (__attribute__((address_space(3))) void*)l, 16, 0, 0);
}

// ---------------------------------------------------------------------------
// x (fp32) -> f16, vectorized 8/thread
// ---------------------------------------------------------------------------
__global__ __launch_bounds__(256) void cvt_f32_f16(
    const float* __restrict__ in, f16* __restrict__ out, int n8)
{
    const int i = blockIdx.x * 256 + threadIdx.x;
    if (i < n8) {
        const float4 a = *(const float4*)(in + (size_t)i * 8);
        const float4 b = *(const float4*)(in + (size_t)i * 8 + 4);
        f16x8 v;
        v[0] = (f16)a.x; v[1] = (f16)a.y; v[2] = (f16)a.z; v[3] = (f16)a.w;
        v[4] = (f16)b.x; v[5] = (f16)b.y; v[6] = (f16)b.z; v[7] = (f16)b.w;
        *(f16x8*)(out + (size_t)i * 8) = v;
    }
}

__global__ __launch_bounds__(256) void concat_bias(
    const float* __restrict__ bq, const float* __restrict__ bk,
    const float* __restrict__ bv, float* __restrict__ bqkv)
{
    const int i = blockIdx.x * 256 + threadIdx.x;
    if (i < QKV_LD)
        bqkv[i] = (i < 768) ? bq[i] : (i < 1536) ? bk[i - 768] : bv[i - 1536];
}

// ---------------------------------------------------------------------------
// All four W[768][768] fp32 -> W^T f16 in one launch (z selects matrix)
// ---------------------------------------------------------------------------
__global__ __launch_bounds__(256) void transpose_cvt_all(
    const float* __restrict__ Wq, const float* __restrict__ Wk,
    const float* __restrict__ Wv, const float* __restrict__ Wo,
    f16* __restrict__ Wqkv_t, f16* __restrict__ Wo_t)
{
    const int z = blockIdx.z;
    const float* src = (z == 0) ? Wq : (z == 1) ? Wk : (z == 2) ? Wv : Wo;
    f16* dst = (z < 3) ? (Wqkv_t + (size_t)z * 768 * 768) : Wo_t;

    __shared__ f16 tile[64][72];
    const int t  = threadIdx.x;
    const int k0 = blockIdx.y * 64;
    const int n0 = blockIdx.x * 64;
    {
        const int r  = t >> 4;
        const int c4 = (t & 15) * 4;
        #pragma unroll
        for (int u = 0; u < 4; ++u) {
            const int row = r + u * 16;
            const float4 a = *(const float4*)&src[(size_t)(k0 + row) * 768 + n0 + c4];
            tile[row][c4 + 0] = (f16)a.x;
            tile[row][c4 + 1] = (f16)a.y;
            tile[row][c4 + 2] = (f16)a.z;
            tile[row][c4 + 3] = (f16)a.w;
        }
    }
    __syncthreads();
    {
        const int rn = t >> 3;
        const int ck = (t & 7) * 8;
        #pragma unroll
        for (int u = 0; u < 2; ++u) {
            const int n = rn + u * 32;
            f16x8 v;
            #pragma unroll
            for (int q = 0; q < 8; ++q) v[q] = tile[ck + q][n];
            *(f16x8*)&dst[(size_t)(n0 + n) * 768 + k0 + ck] = v;
        }
    }
}

// ---------------------------------------------------------------------------
// C[M][N] = A[M][K]f16 @ Bt[N][K]f16^T + bias.  128x128 tile, 4 waves,
// 64x64/wave. global_load_lds(16B) staging, add-rotate k-slot swizzle.
// 1D grid with XCD-contiguous chunk mapping (grid % 8 == 0).
// ---------------------------------------------------------------------------
template<typename OUT_T>
__global__ __launch_bounds__(256) void gemm_f16_tn(
    const f16* __restrict__ A, const f16* __restrict__ Bt,
    const float* __restrict__ bias, OUT_T* __restrict__ C,
    int M, int N, int K, int nb)
{
    __shared__ f16 As[128 * 32];
    __shared__ f16 Bs[128 * 32];

    const int t    = threadIdx.x;
    const int l    = t & 63;
    const int w    = t >> 6;
    const int l15  = l & 15;
    const int lg   = l >> 4;
    const int wrow = (w >> 1) * 64;
    const int wcol = (w & 1) * 64;

    const int orig = blockIdx.x;
    const int cpx  = gridDim.x >> 3;
    const int nid  = (orig & 7) * cpx + (orig >> 3);
    const int row0 = (nid / nb) * 128;
    const int col0 = (nid % nb) * 128;

    int src_row[2], src_koff[2], lds_off[2];
    #pragma unroll
    for (int i = 0; i < 2; ++i) {
        const int c = t + 256 * i;
        const int r = c >> 2;
        src_row[i]  = r;
        src_koff[i] = (((c & 3) - (r >> 1)) & 3) * 8;
        lds_off[i]  = c * 16;
    }

    int a_off[4], b_off[4];
    #pragma unroll
    for (int i = 0; i < 4; ++i) {
        const int ra = wrow + i * 16 + l15;
        a_off[i] = ra * 64 + (((lg + (ra >> 1)) & 3) * 16);
        const int rb = wcol + i * 16 + l15;
        b_off[i] = rb * 64 + (((lg + (rb >> 1)) & 3) * 16);
    }

    f32x4 acc[4][4];
    #pragma unroll
    for (int i = 0; i < 4; ++i)
        #pragma unroll
        for (int j = 0; j < 4; ++j)
            acc[i][j] = (f32x4){0.f, 0.f, 0.f, 0.f};

    const f16* Abase = A  + (size_t)row0 * K;
    const f16* Bbase = Bt + (size_t)col0 * K;

    for (int k0 = 0; k0 < K; k0 += 32) {
        #pragma unroll
        for (int i = 0; i < 2; ++i) {
            gload_lds16(Abase + (size_t)src_row[i] * K + k0 + src_koff[i],
                        (char*)As + lds_off[i]);
            gload_lds16(Bbase + (size_t)src_row[i] * K + k0 + src_koff[i],
                        (char*)Bs + lds_off[i]);
        }
        __syncthreads();

        f16x8 af[4], bf[4];
        #pragma unroll
        for (int i = 0; i < 4; ++i) {
            af[i] = *(const f16x8*)((const char*)As + a_off[i]);
            bf[i] = *(const f16x8*)((const char*)Bs + b_off[i]);
        }
        #pragma unroll
        for (int i = 0; i < 4; ++i)
            #pragma unroll
            for (int j = 0; j < 4; ++j)
                acc[i][j] = __builtin_amdgcn_mfma_f32_16x16x32_f16(
                    af[i], bf[j], acc[i][j], 0, 0, 0);
        __syncthreads();
    }

    #pragma unroll
    for (int j = 0; j < 4; ++j) {
        const int col = col0 + wcol + j * 16 + l15;
        const float bj = bias[col];
        #pragma unroll
        for (int i = 0; i < 4; ++i) {
            const int row = row0 + wrow + i * 16 + lg * 4;
            #pragma unroll
            for (int q = 0; q < 4; ++q)
                C[(size_t)(row + q) * N + col] = (OUT_T)(acc[i][j][q] + bj);
        }
    }
}

// ---------------------------------------------------------------------------
// Flash attention, f16. QBLK=64 (16 q-rows per wave), swapped QK^T,
// exp2 softmax + defer-max, dbuf K/V (1 barrier/kt), all LDS XOR-swizzled
// (proven round-4/5 pattern: write key = row&7, read key = l15&7),
// V transposed (row = d) via scalar swizzled writes, setprio on MFMA.
// grid = 1536 1D, XCD-contiguous. LDS 40KB -> 4 blocks/CU.
// ---------------------------------------------------------------------------
#define RESCALE_THR 10.0f   // exp2 domain; P bounded by 2^10, safe in f16

__global__ __launch_bounds__(256, 4) void attn_f16(
    const f16* __restrict__ QKV, f16* __restrict__ O)
{
    __shared__ f16 KsB[2][64 * 64];   // [k][d], XOR-swizzled 128B rows
    __shared__ f16 VtB[2][64 * 64];   // [d][k], XOR-swizzled 128B rows
    __shared__ f16 PsS[64 * 64];      // [q][k], XOR-swizzled, wave-private rows

    const int t   = threadIdx.x;
    const int w   = t >> 6;
    const int l   = t & 63;
    const int l15 = l & 15;
    const int lg  = l >> 4;
    const int sl  = (l15 & 7) << 4;   // read-side XOR slot key (row&7)

    const int orig = blockIdx.x;                 // 0..1535
    const int s    = (orig & 7) * 192 + (orig >> 3);
    const int bh   = s >> 4;                     // 0..95
    const int qb   = s & 15;                     // 0..15
    const int b  = bh / NHEAD;
    const int h  = bh % NHEAD;
    const int q0 = qb * 64;

    const size_t rowbase = (size_t)b * SEQ;
    const int qcol = h * HDIM;
    const int kcol = 768 + h * HDIM;
    const int vcol = 1536 + h * HDIM;

    // ---- hoist Q fragments (16 q-rows per wave), fold scale*log2e ----
    const f16 hsc = (f16)(0.125f * 1.4426950408889634f);
    f16x8 qf[2];
    #pragma unroll
    for (int dc = 0; dc < 2; ++dc) {
        f16x8 v = *(const f16x8*)(QKV
            + (rowbase + q0 + w * 16 + l15) * QKV_LD
            + qcol + dc * 32 + lg * 8);
        #pragma unroll
        for (int j = 0; j < 8; ++j) v[j] *= hsc;
        qf[dc] = v;
    }

    f32x4 ctx[4];
    #pragma unroll
    for (int d2 = 0; d2 < 4; ++d2) ctx[d2] = (f32x4){0.f, 0.f, 0.f, 0.f};
    float mrun = -INFINITY;
    float lrun = 0.f;

    // ---- staging: row k = l, 16-col chunk cb = w*16 ----
    const int cb = w * 16;
    const f16* kptr = QKV + (rowbase + l) * QKV_LD + kcol + cb;
    const f16* vptr = QKV + (rowbase + l) * QKV_LD + vcol + cb;
    const size_t step = (size_t)64 * QKV_LD;

    f16x8 kr0 = *(const f16x8*)(kptr);
    f16x8 kr1 = *(const f16x8*)(kptr + 8);
    f16x8 vr0 = *(const f16x8*)(vptr);
    f16x8 vr1 = *(const f16x8*)(vptr + 8);

    // stage tile 0 -> buf 0  (V transposed: row d = cb+j / cb+8+j, col k = l)
    {
        char* Kd = (char*)KsB[0];
        char* Vd = (char*)VtB[0];
        *(f16x8*)(Kd + l * 128 + ((cb * 2)      ^ ((l & 7) << 4))) = kr0;
        *(f16x8*)(Kd + l * 128 + ((cb * 2 + 16) ^ ((l & 7) << 4))) = kr1;
        #pragma unroll
        for (int j = 0; j < 8; ++j) {
            *(f16*)(Vd + (cb + j)     * 128 + ((l * 2) ^ (j << 4))) = vr0[j];
            *(f16*)(Vd + (cb + 8 + j) * 128 + ((l * 2) ^ (j << 4))) = vr1[j];
        }
    }
    kr0 = *(const f16x8*)(kptr + step);
    kr1 = *(const f16x8*)(kptr + step + 8);
    vr0 = *(const f16x8*)(vptr + step);
    vr1 = *(const f16x8*)(vptr + step + 8);
    __syncthreads();

    for (int kt = 0; kt < SEQ / 64; ++kt) {
        const int p = kt & 1;
        const char* Kp = (const char*)KsB[p];
        const char* Vp = (const char*)VtB[p];
        char* Pp = (char*)PsS;

        // ---- S^T = K @ Q^T : lane holds k = kc*16+lg*4+r for q = l15 ----
        f32x4 sc[4];
        __builtin_amdgcn_s_setprio(1);
        #pragma unroll
        for (int kc = 0; kc < 4; ++kc) {
            const int rk = kc * 16 + l15;
            const f16x8 ka0 = *(const f16x8*)(Kp + rk * 128 + ((lg * 16)      ^ sl));
            const f16x8 ka1 = *(const f16x8*)(Kp + rk * 128 + ((64 + lg * 16) ^ sl));
            f32x4 a = (f32x4){0.f, 0.f, 0.f, 0.f};
            a = __builtin_amdgcn_mfma_f32_16x16x32_f16(ka0, qf[0], a, 0, 0, 0);
            a = __builtin_amdgcn_mfma_f32_16x16x32_f16(ka1, qf[1], a, 0, 0, 0);
            sc[kc] = a;
        }
        __builtin_amdgcn_s_setprio(0);

        // ---- softmax (exp2 domain, scale pre-folded, defer-max) ----
        {
            float tmax = fmaxf(fmaxf(sc[0][0], sc[0][1]), fmaxf(sc[0][2], sc[0][3]));
            #pragma unroll
            for (int kc = 1; kc < 4; ++kc)
                tmax = fmaxf(tmax, fmaxf(fmaxf(sc[kc][0], sc[kc][1]),
                                         fmaxf(sc[kc][2], sc[kc][3])));
            tmax = fmaxf(tmax, __shfl_xor(tmax, 16));
            tmax = fmaxf(tmax, __shfl_xor(tmax, 32));

            if (__any(tmax > mrun + RESCALE_THR)) {
                const float mnew = fmaxf(mrun, tmax);
                const float corr = exp2f(mrun - mnew);
                mrun = mnew;
                lrun *= corr;
                float cr[4];
                #pragma unroll
                for (int r = 0; r < 4; ++r)
                    cr[r] = __shfl(corr, lg * 4 + r);
                #pragma unroll
                for (int dcol = 0; dcol < 4; ++dcol)
                    #pragma unroll
                    for (int r = 0; r < 4; ++r)
                        ctx[dcol][r] *= cr[r];
            }

            float ps = 0.f;
            const int rowq = w * 16 + l15;
            #pragma unroll
            for (int kc = 0; kc < 4; ++kc) {
                f16x4 pv;
                #pragma unroll
                for (int r = 0; r < 4; ++r) {
                    const float pe = exp2f(sc[kc][r] - mrun);
                    ps += pe;
                    pv[r] = (f16)pe;
                }
                *(f16x4*)(Pp + rowq * 128 + ((kc * 32 + lg * 8) ^ sl)) = pv;
            }
            ps += __shfl_xor(ps, 16);
            ps += __shfl_xor(ps, 32);
            lrun += ps;
        }

        // ---- ctx += P V : both operands via swizzled ds_read_b128 ----
        __builtin_amdgcn_s_setprio(1);
        #pragma unroll
        for (int kc2 = 0; kc2 < 2; ++kc2) {
            const int cbyte = (kc2 * 64 + lg * 16) ^ sl;
            const f16x8 pa = *(const f16x8*)(Pp + (w * 16 + l15) * 128 + cbyte);
            #pragma unroll
            for (int sd = 0; sd < 4; ++sd) {
                const f16x8 vb = *(const f16x8*)(Vp + (sd * 16 + l15) * 128 + cbyte);
                ctx[sd] = __builtin_amdgcn_mfma_f32_16x16x32_f16(pa, vb, ctx[sd], 0, 0, 0);
            }
        }
        __builtin_amdgcn_s_setprio(0);

        // ---- stage tile kt+1 into buf p^1; issue loads for kt+2 ----
        if (kt < SEQ / 64 - 1) {
            char* Kd = (char*)KsB[p ^ 1];
            char* Vd = (char*)VtB[p ^ 1];
            *(f16x8*)(Kd + l * 128 + ((cb * 2)      ^ ((l & 7) << 4))) = kr0;
            *(f16x8*)(Kd + l * 128 + ((cb * 2 + 16) ^ ((l & 7) << 4))) = kr1;
            #pragma unroll
            for (int j = 0; j < 8; ++j) {
                *(f16*)(Vd + (cb + j)     * 128 + ((l * 2) ^ (j << 4))) = vr0[j];
                *(f16*)(Vd + (cb + 8 + j) * 128 + ((l * 2) ^ (j << 4))) = vr1[j];
            }
            if (kt < SEQ / 64 - 2) {
                const f16* kp = kptr + (size_t)(kt + 2) * step;
                const f16* vp = vptr + (size_t)(kt + 2) * step;
                kr0 = *(const f16x8*)(kp);
                kr1 = *(const f16x8*)(kp + 8);
                vr0 = *(const f16x8*)(vp);
                vr1 = *(const f16x8*)(vp + 8);
            }
        }
        __syncthreads();
    }

    // ---- normalize + store f16 ctx (q = q0 + w*16 + lg*4 + r) ----
    {
        const float inv = 1.0f / lrun;
        float iv[4];
        #pragma unroll
        for (int r = 0; r < 4; ++r)
            iv[r] = __shfl(inv, lg * 4 + r);
        #pragma unroll
        for (int r = 0; r < 4; ++r) {
            const size_t row = rowbase + q0 + w * 16 + lg * 4 + r;
            #pragma unroll
            for (int dcol = 0; dcol < 4; ++dcol)
                O[row * D_MODEL + qcol + dcol * 16 + l15] = (f16)(ctx[dcol][r] * iv[r]);
        }
    }
}

// ---------------------------------------------------------------------------
extern "C" void kernel_launch(void* const* d_in, const int* in_sizes, int n_in,
                              void* d_out, int out_size, void* d_ws, size_t ws_size,
                              hipStream_t stream) {
    const float* x  = (const float*)d_in[0];
    const float* Wq = (const float*)d_in[1];
    const float* bq = (const float*)d_in[2];
    const float* Wk = (const float*)d_in[3];
    const float* bk = (const float*)d_in[4];
    const float* Wv = (const float*)d_in[5];
    const float* bv = (const float*)d_in[6];
    const float* Wo = (const float*)d_in[7];
    const float* bo = (const float*)d_in[8];
    float* out = (float*)d_out;

    char* ws = (char*)d_ws;
    f16*   QKV     = (f16*)(ws);                                   // 37,748,736 B
    f16*   xh      = (f16*)(ws + 37748736);                        // 12,582,912
    f16*   ctxh    = (f16*)(ws + 37748736 + 12582912);             // 12,582,912
    f16*   Wqkv_t  = (f16*)(ws + 37748736 + 2 * 12582912);         // 3,538,944
    f16*   Wo_t    = (f16*)(ws + 37748736 + 2 * 12582912 + 3538944);       // 1,179,648
    float* bqkv    = (float*)(ws + 37748736 + 2 * 12582912 + 3538944 + 1179648);

    hipLaunchKernelGGL(cvt_f32_f16, dim3(MTOT * D_MODEL / 8 / 256), dim3(256), 0, stream,
                       x, xh, MTOT * D_MODEL / 8);
    hipLaunchKernelGGL(concat_bias, dim3(9), dim3(256), 0, stream, bq, bk, bv, bqkv);
    hipLaunchKernelGGL(transpose_cvt_all, dim3(12, 12, 4), dim3(256), 0, stream,
                       Wq, Wk, Wv, Wo, Wqkv_t, Wo_t);

    // fused QKV projection: grid 18*64 = 1152 (XCD-chunked inside kernel)
    hipLaunchKernelGGL((gemm_f16_tn<f16>), dim3((QKV_LD / 128) * (MTOT / 128)), dim3(256), 0, stream,
                       xh, Wqkv_t, bqkv, QKV, MTOT, QKV_LD, D_MODEL, QKV_LD / 128);

    hipLaunchKernelGGL(attn_f16, dim3((SEQ / 64) * BATCH * NHEAD), dim3(256), 0, stream,
                       QKV, ctxh);

    // output projection: grid 6*64 = 384
    hipLaunchKernelGGL((gemm_f16_tn<float>), dim3((D_MODEL / 128) * (MTOT / 128)), dim3(256), 0, stream,
                       ctxh, Wo_t, bo, out, MTOT, D_MODEL, D_MODEL, D_MODEL / 128);
}

// Round 9
// 139.777 us; speedup vs baseline: 8.4451x; 1.0443x over previous
//
#include <hip/hip_runtime.h>
#include <math.h>

#define D_MODEL 768
#define NHEAD  12
#define HDIM   64
#define SEQ    1024
#define BATCH  8
#define MTOT   (BATCH*SEQ)   // 8192
#define QKV_LD 2304          // Q|K|V concatenated columns

typedef _Float16 f16;
typedef __attribute__((ext_vector_type(2))) __fp16 fp16x2;
typedef __attribute__((ext_vector_type(4))) _Float16 f16x4;
typedef __attribute__((ext_vector_type(8))) _Float16 f16x8;
typedef __attribute__((ext_vector_type(4))) float f32x4;
typedef __attribute__((ext_vector_type(16))) float f32x16;

union PFrag { unsigned u[4]; f16x8 v; };
union PackW { fp16x2 h; unsigned u; };

__device__ inline void gload_lds16(const void* g, void* l) {
    __builtin_amdgcn_global_load_lds(
        (const __attribute__((address_space(1))) void*)g,
        (__attribute__((address_space(3))) void*)l, 16, 0, 0);
}

// ---------------------------------------------------------------------------
// x (fp32) -> f16, vectorized 8/thread
// ---------------------------------------------------------------------------
__global__ __launch_bounds__(256) void cvt_f32_f16(
    const float* __restrict__ in, f16* __restrict__ out, int n8)
{
    const int i = blockIdx.x * 256 + threadIdx.x;
    if (i < n8) {
        const float4 a = *(const float4*)(in + (size_t)i * 8);
        const float4 b = *(const float4*)(in + (size_t)i * 8 + 4);
        f16x8 v;
        v[0] = (f16)a.x; v[1] = (f16)a.y; v[2] = (f16)a.z; v[3] = (f16)a.w;
        v[4] = (f16)b.x; v[5] = (f16)b.y; v[6] = (f16)b.z; v[7] = (f16)b.w;
        *(f16x8*)(out + (size_t)i * 8) = v;
    }
}

__global__ __launch_bounds__(256) void concat_bias(
    const float* __restrict__ bq, const float* __restrict__ bk,
    const float* __restrict__ bv, float* __restrict__ bqkv)
{
    const int i = blockIdx.x * 256 + threadIdx.x;
    if (i < QKV_LD)
        bqkv[i] = (i < 768) ? bq[i] : (i < 1536) ? bk[i - 768] : bv[i - 1536];
}

// ---------------------------------------------------------------------------
// All four W[768][768] fp32 -> W^T f16 in one launch (z selects matrix)
// ---------------------------------------------------------------------------
__global__ __launch_bounds__(256) void transpose_cvt_all(
    const float* __restrict__ Wq, const float* __restrict__ Wk,
    const float* __restrict__ Wv, const float* __restrict__ Wo,
    f16* __restrict__ Wqkv_t, f16* __restrict__ Wo_t)
{
    const int z = blockIdx.z;
    const float* src = (z == 0) ? Wq : (z == 1) ? Wk : (z == 2) ? Wv : Wo;
    f16* dst = (z < 3) ? (Wqkv_t + (size_t)z * 768 * 768) : Wo_t;

    __shared__ f16 tile[64][72];
    const int t  = threadIdx.x;
    const int k0 = blockIdx.y * 64;
    const int n0 = blockIdx.x * 64;
    {
        const int r  = t >> 4;
        const int c4 = (t & 15) * 4;
        #pragma unroll
        for (int u = 0; u < 4; ++u) {
            const int row = r + u * 16;
            const float4 a = *(const float4*)&src[(size_t)(k0 + row) * 768 + n0 + c4];
            tile[row][c4 + 0] = (f16)a.x;
            tile[row][c4 + 1] = (f16)a.y;
            tile[row][c4 + 2] = (f16)a.z;
            tile[row][c4 + 3] = (f16)a.w;
        }
    }
    __syncthreads();
    {
        const int rn = t >> 3;
        const int ck = (t & 7) * 8;
        #pragma unroll
        for (int u = 0; u < 2; ++u) {
            const int n = rn + u * 32;
            f16x8 v;
            #pragma unroll
            for (int q = 0; q < 8; ++q) v[q] = tile[ck + q][n];
            *(f16x8*)&dst[(size_t)(n0 + n) * 768 + k0 + ck] = v;
        }
    }
}

// ---------------------------------------------------------------------------
// C[M][N] = A[M][K]f16 @ Bt[N][K]f16^T + bias.  128x128 tile, 4 waves,
// 64x64/wave. global_load_lds(16B) staging, add-rotate k-slot swizzle.
// 1D grid with XCD-contiguous chunk mapping (grid % 8 == 0).
// ---------------------------------------------------------------------------
template<typename OUT_T>
__global__ __launch_bounds__(256) void gemm_f16_tn(
    const f16* __restrict__ A, const f16* __restrict__ Bt,
    const float* __restrict__ bias, OUT_T* __restrict__ C,
    int M, int N, int K, int nb)
{
    __shared__ f16 As[128 * 32];
    __shared__ f16 Bs[128 * 32];

    const int t    = threadIdx.x;
    const int l    = t & 63;
    const int w    = t >> 6;
    const int l15  = l & 15;
    const int lg   = l >> 4;
    const int wrow = (w >> 1) * 64;
    const int wcol = (w & 1) * 64;

    const int orig = blockIdx.x;
    const int cpx  = gridDim.x >> 3;
    const int nid  = (orig & 7) * cpx + (orig >> 3);
    const int row0 = (nid / nb) * 128;
    const int col0 = (nid % nb) * 128;

    int src_row[2], src_koff[2], lds_off[2];
    #pragma unroll
    for (int i = 0; i < 2; ++i) {
        const int c = t + 256 * i;
        const int r = c >> 2;
        src_row[i]  = r;
        src_koff[i] = (((c & 3) - (r >> 1)) & 3) * 8;
        lds_off[i]  = c * 16;
    }

    int a_off[4], b_off[4];
    #pragma unroll
    for (int i = 0; i < 4; ++i) {
        const int ra = wrow + i * 16 + l15;
        a_off[i] = ra * 64 + (((lg + (ra >> 1)) & 3) * 16);
        const int rb = wcol + i * 16 + l15;
        b_off[i] = rb * 64 + (((lg + (rb >> 1)) & 3) * 16);
    }

    f32x4 acc[4][4];
    #pragma unroll
    for (int i = 0; i < 4; ++i)
        #pragma unroll
        for (int j = 0; j < 4; ++j)
            acc[i][j] = (f32x4){0.f, 0.f, 0.f, 0.f};

    const f16* Abase = A  + (size_t)row0 * K;
    const f16* Bbase = Bt + (size_t)col0 * K;

    for (int k0 = 0; k0 < K; k0 += 32) {
        #pragma unroll
        for (int i = 0; i < 2; ++i) {
            gload_lds16(Abase + (size_t)src_row[i] * K + k0 + src_koff[i],
                        (char*)As + lds_off[i]);
            gload_lds16(Bbase + (size_t)src_row[i] * K + k0 + src_koff[i],
                        (char*)Bs + lds_off[i]);
        }
        __syncthreads();

        f16x8 af[4], bf[4];
        #pragma unroll
        for (int i = 0; i < 4; ++i) {
            af[i] = *(const f16x8*)((const char*)As + a_off[i]);
            bf[i] = *(const f16x8*)((const char*)Bs + b_off[i]);
        }
        #pragma unroll
        for (int i = 0; i < 4; ++i)
            #pragma unroll
            for (int j = 0; j < 4; ++j)
                acc[i][j] = __builtin_amdgcn_mfma_f32_16x16x32_f16(
                    af[i], bf[j], acc[i][j], 0, 0, 0);
        __syncthreads();
    }

    #pragma unroll
    for (int j = 0; j < 4; ++j) {
        const int col = col0 + wcol + j * 16 + l15;
        const float bj = bias[col];
        #pragma unroll
        for (int i = 0; i < 4; ++i) {
            const int row = row0 + wrow + i * 16 + lg * 4;
            #pragma unroll
            for (int q = 0; q < 4; ++q)
                C[(size_t)(row + q) * N + col] = (OUT_T)(acc[i][j][q] + bj);
        }
    }
}

// ---------------------------------------------------------------------------
// Flash attention, f16, 32x32x16 MFMA. QBLK=128 (32 q-rows/wave), KVB=64.
// Swapped QK^T (S^T: lane-local q = l&31, k in 16 regs via
// krow=(reg&3)+8*(reg>>2)+4*(l>>5)); exp2 softmax + defer-max; P packed
// in-register (cvt_pkrtz) and redistributed with 8 shfl_xor(32) -> PV
// A-operand never touches LDS. K and V^T staged in XOR-swizzled LDS
// (128B rows, key=(row&7)<<4), double-buffered, 1 barrier/kt.
// grid = 768 1D, XCD-contiguous. LDS 32KB.
// ---------------------------------------------------------------------------
#define RESCALE_THR 10.0f   // exp2 domain; P bounded by 2^10, safe in f16
#define QMAP(r, hh) (((r) & 3) + 8 * ((r) >> 2) + 4 * (hh))

__global__ __launch_bounds__(256, 3) void attn_f16(
    const f16* __restrict__ QKV, f16* __restrict__ O)
{
    __shared__ f16 KsB[2][64 * 64];   // [k][d], swizzled
    __shared__ f16 VtB[2][64 * 64];   // [d][k], swizzled

    const int t   = threadIdx.x;
    const int w   = t >> 6;
    const int l   = t & 63;
    const int l31 = l & 31;
    const int h   = l >> 5;
    const int sl  = (l & 7) << 4;     // read/write XOR key for row=l31/l (row&7)

    const int orig = blockIdx.x;                 // 0..767
    const int s    = (orig & 7) * 96 + (orig >> 3);
    const int bh   = s >> 3;                     // 0..95
    const int qb   = s & 7;                      // 0..7
    const int b  = bh / NHEAD;
    const int hd = bh % NHEAD;
    const int q0 = qb * 128;

    const size_t rowbase = (size_t)b * SEQ;
    const int qcol = hd * HDIM;
    const int kcol = 768 + hd * HDIM;
    const int vcol = 1536 + hd * HDIM;

    // ---- hoist Q fragments (B-operand: col=l31=q, k=h*8+j per 16-d chunk) --
    const f16 hsc = (f16)(0.125f * 1.4426950408889634f);
    f16x8 qf[4];
    #pragma unroll
    for (int dc = 0; dc < 4; ++dc) {
        f16x8 v = *(const f16x8*)(QKV
            + (rowbase + q0 + w * 32 + l31) * QKV_LD
            + qcol + dc * 16 + h * 8);
        #pragma unroll
        for (int j = 0; j < 8; ++j) v[j] *= hsc;
        qf[dc] = v;
    }

    f32x16 ctx[2];
    #pragma unroll
    for (int dt = 0; dt < 2; ++dt)
        #pragma unroll
        for (int r = 0; r < 16; ++r) ctx[dt][r] = 0.f;
    float mrun = -INFINITY;
    float lrun = 0.f;

    // ---- staging addresses ----
    const int cb  = w * 16;                 // K: row k=l, 16-d chunk
    const int vk0 = (l & 15) * 4;           // V: 4k x 4d block per thread
    const int vd0 = ((l >> 4) + 4 * w) * 4;
    const f16* kptr = QKV + (rowbase + l)   * QKV_LD + kcol + cb;
    const f16* vptr = QKV + (rowbase + vk0) * QKV_LD + vcol + vd0;
    const size_t step = (size_t)64 * QKV_LD;

    f16x8 kr0, kr1;
    f16x4 vr[4];
    kr0 = *(const f16x8*)(kptr);
    kr1 = *(const f16x8*)(kptr + 8);
    #pragma unroll
    for (int i = 0; i < 4; ++i)
        vr[i] = *(const f16x4*)(vptr + (size_t)i * QKV_LD);

    // stage tile 0 -> buf 0
    {
        char* Kd = (char*)KsB[0];
        char* Vd = (char*)VtB[0];
        *(f16x8*)(Kd + l * 128 + ((cb * 2)      ^ sl)) = kr0;
        *(f16x8*)(Kd + l * 128 + ((cb * 2 + 16) ^ sl)) = kr1;
        #pragma unroll
        for (int di = 0; di < 4; ++di) {
            f16x4 wt;
            #pragma unroll
            for (int i = 0; i < 4; ++i) wt[i] = vr[i][di];
            *(f16x4*)(Vd + (vd0 + di) * 128
                         + ((vk0 * 2) ^ (((vd0 + di) & 7) << 4))) = wt;
        }
    }
    kr0 = *(const f16x8*)(kptr + step);
    kr1 = *(const f16x8*)(kptr + step + 8);
    #pragma unroll
    for (int i = 0; i < 4; ++i)
        vr[i] = *(const f16x4*)(vptr + step + (size_t)i * QKV_LD);
    __syncthreads();

    for (int kt = 0; kt < SEQ / 64; ++kt) {
        const int p = kt & 1;
        const char* Kp = (const char*)KsB[p];
        const char* Vp = (const char*)VtB[p];

        // ---- S^T = K @ Q^T : 2 k-tiles of 32x32, contraction d=64 ----
        f32x16 sacc[2];
        __builtin_amdgcn_s_setprio(1);
        #pragma unroll
        for (int kk = 0; kk < 2; ++kk) {
            f32x16 a;
            #pragma unroll
            for (int r = 0; r < 16; ++r) a[r] = 0.f;
            #pragma unroll
            for (int dc = 0; dc < 4; ++dc) {
                const f16x8 ka = *(const f16x8*)(Kp + (kk * 32 + l31) * 128
                                                    + ((dc * 32 + h * 16) ^ sl));
                a = __builtin_amdgcn_mfma_f32_32x32x16_f16(ka, qf[dc], a, 0, 0, 0);
            }
            sacc[kk] = a;
        }
        __builtin_amdgcn_s_setprio(0);

        // ---- softmax (exp2 domain, scale pre-folded, defer-max) ----
        {
            float tmax = sacc[0][0];
            #pragma unroll
            for (int r = 1; r < 16; ++r) tmax = fmaxf(tmax, sacc[0][r]);
            #pragma unroll
            for (int r = 0; r < 16; ++r) tmax = fmaxf(tmax, sacc[1][r]);
            tmax = fmaxf(tmax, __shfl_xor(tmax, 32));

            if (__any(tmax > mrun + RESCALE_THR)) {
                const float mnew = fmaxf(mrun, tmax);
                const float corr = exp2f(mrun - mnew);
                mrun = mnew;
                lrun *= corr;
                #pragma unroll
                for (int r = 0; r < 16; ++r) {
                    const float cr = __shfl(corr, QMAP(r, h));
                    ctx[0][r] *= cr;
                    ctx[1][r] *= cr;
                }
            }

            float ps = 0.f;
            #pragma unroll
            for (int kk = 0; kk < 2; ++kk)
                #pragma unroll
                for (int r = 0; r < 16; ++r) {
                    const float pe = exp2f(sacc[kk][r] - mrun);
                    ps += pe;
                    sacc[kk][r] = pe;
                }
            ps += __shfl_xor(ps, 32);
            lrun += ps;
        }

        // ---- pack P to f16 dwords, redistribute across half-waves ----
        // lane holds P[q=l31][k = kk*32 + (reg&3)+8*(reg>>2)+4h]
        // PV A-frag needs k = c*16 + h*8 + j
        unsigned paw[4][4];
        #pragma unroll
        for (int kk = 0; kk < 2; ++kk) {
            unsigned dw[8];
            #pragma unroll
            for (int i = 0; i < 8; ++i) {
                PackW u;
                u.h = __builtin_amdgcn_cvt_pkrtz(sacc[kk][2 * i], sacc[kk][2 * i + 1]);
                dw[i] = u.u;
            }
            const unsigned t0 = (unsigned)__shfl_xor((int)(h ? dw[0] : dw[2]), 32);
            const unsigned t1 = (unsigned)__shfl_xor((int)(h ? dw[1] : dw[3]), 32);
            const unsigned t2 = (unsigned)__shfl_xor((int)(h ? dw[4] : dw[6]), 32);
            const unsigned t3 = (unsigned)__shfl_xor((int)(h ? dw[5] : dw[7]), 32);
            paw[2 * kk][0]     = h ? t0    : dw[0];
            paw[2 * kk][1]     = h ? t1    : dw[1];
            paw[2 * kk][2]     = h ? dw[2] : t0;
            paw[2 * kk][3]     = h ? dw[3] : t1;
            paw[2 * kk + 1][0] = h ? t2    : dw[4];
            paw[2 * kk + 1][1] = h ? t3    : dw[5];
            paw[2 * kk + 1][2] = h ? dw[6] : t2;
            paw[2 * kk + 1][3] = h ? dw[7] : t3;
        }

        // ---- ctx += P V : A in-register, B = Vt swizzled b128 ----
        __builtin_amdgcn_s_setprio(1);
        #pragma unroll
        for (int c = 0; c < 4; ++c) {
            PFrag pf;
            pf.u[0] = paw[c][0]; pf.u[1] = paw[c][1];
            pf.u[2] = paw[c][2]; pf.u[3] = paw[c][3];
            #pragma unroll
            for (int dt = 0; dt < 2; ++dt) {
                const f16x8 vb = *(const f16x8*)(Vp + (dt * 32 + l31) * 128
                                                    + ((c * 32 + h * 16) ^ sl));
                ctx[dt] = __builtin_amdgcn_mfma_f32_32x32x16_f16(pf.v, vb, ctx[dt], 0, 0, 0);
            }
        }
        __builtin_amdgcn_s_setprio(0);

        // ---- stage tile kt+1 into buf p^1; issue loads for kt+2 ----
        if (kt < SEQ / 64 - 1) {
            char* Kd = (char*)KsB[p ^ 1];
            char* Vd = (char*)VtB[p ^ 1];
            *(f16x8*)(Kd + l * 128 + ((cb * 2)      ^ sl)) = kr0;
            *(f16x8*)(Kd + l * 128 + ((cb * 2 + 16) ^ sl)) = kr1;
            #pragma unroll
            for (int di = 0; di < 4; ++di) {
                f16x4 wt;
                #pragma unroll
                for (int i = 0; i < 4; ++i) wt[i] = vr[i][di];
                *(f16x4*)(Vd + (vd0 + di) * 128
                             + ((vk0 * 2) ^ (((vd0 + di) & 7) << 4))) = wt;
            }
            if (kt < SEQ / 64 - 2) {
                const f16* kp = kptr + (size_t)(kt + 2) * step;
                const f16* vp = vptr + (size_t)(kt + 2) * step;
                kr0 = *(const f16x8*)(kp);
                kr1 = *(const f16x8*)(kp + 8);
                #pragma unroll
                for (int i = 0; i < 4; ++i)
                    vr[i] = *(const f16x4*)(vp + (size_t)i * QKV_LD);
            }
        }
        __syncthreads();
    }

    // ---- normalize + store f16 ctx: lane holds d = dt*32+l31, q = QMAP(r,h)
    {
        const float inv = 1.0f / lrun;
        #pragma unroll
        for (int r = 0; r < 16; ++r) {
            const float iv = __shfl(inv, QMAP(r, h));
            const size_t row = rowbase + q0 + w * 32 + QMAP(r, h);
            O[row * D_MODEL + qcol + l31]      = (f16)(ctx[0][r] * iv);
            O[row * D_MODEL + qcol + 32 + l31] = (f16)(ctx[1][r] * iv);
        }
    }
}

// ---------------------------------------------------------------------------
extern "C" void kernel_launch(void* const* d_in, const int* in_sizes, int n_in,
                              void* d_out, int out_size, void* d_ws, size_t ws_size,
                              hipStream_t stream) {
    const float* x  = (const float*)d_in[0];
    const float* Wq = (const float*)d_in[1];
    const float* bq = (const float*)d_in[2];
    const float* Wk = (const float*)d_in[3];
    const float* bk = (const float*)d_in[4];
    const float* Wv = (const float*)d_in[5];
    const float* bv = (const float*)d_in[6];
    const float* Wo = (const float*)d_in[7];
    const float* bo = (const float*)d_in[8];
    float* out = (float*)d_out;

    char* ws = (char*)d_ws;
    f16*   QKV     = (f16*)(ws);                                   // 37,748,736 B
    f16*   xh      = (f16*)(ws + 37748736);                        // 12,582,912
    f16*   ctxh    = (f16*)(ws + 37748736 + 12582912);             // 12,582,912
    f16*   Wqkv_t  = (f16*)(ws + 37748736 + 2 * 12582912);         // 3,538,944
    f16*   Wo_t    = (f16*)(ws + 37748736 + 2 * 12582912 + 3538944);       // 1,179,648
    float* bqkv    = (float*)(ws + 37748736 + 2 * 12582912 + 3538944 + 1179648);

    hipLaunchKernelGGL(cvt_f32_f16, dim3(MTOT * D_MODEL / 8 / 256), dim3(256), 0, stream,
                       x, xh, MTOT * D_MODEL / 8);
    hipLaunchKernelGGL(concat_bias, dim3(9), dim3(256), 0, stream, bq, bk, bv, bqkv);
    hipLaunchKernelGGL(transpose_cvt_all, dim3(12, 12, 4), dim3(256), 0, stream,
                       Wq, Wk, Wv, Wo, Wqkv_t, Wo_t);

    // fused QKV projection: grid 18*64 = 1152 (XCD-chunked inside kernel)
    hipLaunchKernelGGL((gemm_f16_tn<f16>), dim3((QKV_LD / 128) * (MTOT / 128)), dim3(256), 0, stream,
                       xh, Wqkv_t, bqkv, QKV, MTOT, QKV_LD, D_MODEL, QKV_LD / 128);

    hipLaunchKernelGGL(attn_f16, dim3((SEQ / 128) * BATCH * NHEAD), dim3(256), 0, stream,
                       QKV, ctxh);

    // output projection: grid 6*64 = 384
    hipLaunchKernelGGL((gemm_f16_tn<float>), dim3((D_MODEL / 128) * (MTOT / 128)), dim3(256), 0, stream,
                       ctxh, Wo_t, bo, out, MTOT, D_MODEL, D_MODEL, D_MODEL / 128);
}